// Round 23
// baseline (193.342 us; speedup 1.0000x reference)
//
#include <hip/hip_runtime.h>
#include <hip/hip_bf16.h>
#include <math.h>

typedef unsigned short ushort_t; // bf16 bits
typedef __attribute__((ext_vector_type(4))) short s16x4;
typedef __attribute__((ext_vector_type(8))) short short8;
typedef __attribute__((ext_vector_type(8))) __bf16 bf16x8;
typedef __attribute__((ext_vector_type(4))) float f32x4;
typedef __attribute__((ext_vector_type(4))) unsigned u32x4;

#define SDIM 2048
#define EDIM 768
#define NTOK 4096

static __device__ __forceinline__ ushort_t f2bf(float f) {
  unsigned u = __builtin_bit_cast(unsigned, f);
  u += 0x7fff + ((u >> 16) & 1);
  return (ushort_t)(u >> 16);
}
static __device__ __forceinline__ float bf2f(ushort_t h) {
  return __builtin_bit_cast(float, (unsigned)h << 16);
}
static __device__ __forceinline__ f32x4 mfma16(short8 a, short8 b, f32x4 c) {
  return __builtin_amdgcn_mfma_f32_16x16x32_bf16(
      __builtin_bit_cast(bf16x8, a), __builtin_bit_cast(bf16x8, b), c, 0, 0, 0);
}
static __device__ __forceinline__ void gload_lds16(const void* g, void* l) {
  __builtin_amdgcn_global_load_lds(
      (const __attribute__((address_space(1))) void*)g,
      (__attribute__((address_space(3))) void*)l, 16, 0, 0);
}
static __device__ __forceinline__ unsigned cvtpk(float lo, float hi) {
  unsigned r;
  asm("v_cvt_pk_bf16_f32 %0, %1, %2" : "=v"(r) : "v"(lo), "v"(hi));
  return r;
}
static __device__ __forceinline__ float exp2fast(float x) {
  float r;
  asm("v_exp_f32 %0, %1" : "=v"(r) : "v"(x));
  return r;
}

// ---------- merged preprocessing ----------
// grid (24, 611), block (32,8):
//   y in [0,120): five 768x768 cast+transpose jobs (y/24 selects weight)
//   y in [120,216): w2 [3072][768] -> w2T [768][3072]
//   y in [216,312): w1 shifted copies w1s[i][e][m] = w1[e][i+m]
//   y in [312,483): LayerNorm1 rows (row = (y-312)*24 + blockIdx.x)
//   y in [483,611): b1eff[n], n = (y-483)*24 + blockIdx.x (256-thr reduction)
__global__ void k_pre(const float* __restrict__ wq, const float* __restrict__ wk,
                      const float* __restrict__ wv, const float* __restrict__ wo,
                      const float* __restrict__ wvqc, const float* __restrict__ w2,
                      const float* __restrict__ w1, const float* __restrict__ x,
                      const float* __restrict__ ln1g, const float* __restrict__ ln1b,
                      const float* __restrict__ b1, const float* __restrict__ bvqc,
                      ushort_t* __restrict__ oqkv, ushort_t* __restrict__ owo,
                      ushort_t* __restrict__ ovqc, ushort_t* __restrict__ w2T,
                      ushort_t* __restrict__ w1s, ushort_t* __restrict__ xn,
                      float* __restrict__ b1e) {
  const int y = blockIdx.y;
  const int tx = threadIdx.x, ty = threadIdx.y;
  __shared__ float tile[32][33];
  __shared__ float red[8];
  if (y < 216) {
    const float* in;
    ushort_t* out;
    int R, r0;
    const int c0 = blockIdx.x * 32;
    if (y < 120) {
      const int z = y / 24, ry = y - z * 24;
      in = z == 0 ? wq : z == 1 ? wk : z == 2 ? wv : z == 3 ? wo : wvqc;
      out = z < 3 ? oqkv + (size_t)z * 768 * 768 : (z == 3 ? owo : ovqc);
      R = 768;
      r0 = ry * 32;
    } else {
      in = w2;
      out = w2T;
      R = 3072;
      r0 = (y - 120) * 32;
    }
#pragma unroll
    for (int i = 0; i < 32; i += 8)
      tile[ty + i][tx] = in[(size_t)(r0 + ty + i) * 768 + c0 + tx];
    __syncthreads();
#pragma unroll
    for (int i = 0; i < 32; i += 8)
      out[(size_t)(c0 + ty + i) * R + r0 + tx] = f2bf(tile[tx][ty + i]);
  } else if (y < 312) {
    const int idx = ((y - 216) * 24 + blockIdx.x) * 256 + ty * 32 + tx;
    const int e = idx / 768, m = idx - (idx / 768) * 768;
#pragma unroll
    for (int i = 0; i < 4; i++)
      w1s[((size_t)i * 768 + e) * 768 + m] = f2bf(w1[(size_t)e * 3072 + i + m]);
  } else if (y < 483) {
    const int row = (y - 312) * 24 + blockIdx.x;
    if (row >= NTOK) return;
    const int t = ty * 32 + tx;
    const float* xr = x + (size_t)row * EDIM;
    float v0 = xr[t], v1 = xr[t + 256], v2 = xr[t + 512];
    float s = v0 + v1 + v2;
    float s2 = v0 * v0 + v1 * v1 + v2 * v2;
#pragma unroll
    for (int m = 32; m; m >>= 1) {
      s += __shfl_xor(s, m);
      s2 += __shfl_xor(s2, m);
    }
    const int wid = t >> 6, lane = t & 63;
    if (lane == 0) { red[wid] = s; red[4 + wid] = s2; }
    __syncthreads();
    s = red[0] + red[1] + red[2] + red[3];
    s2 = red[4] + red[5] + red[6] + red[7];
    float mean = s * (1.f / EDIM);
    float var = s2 * (1.f / EDIM) - mean * mean;
    float rstd = rsqrtf(var + 1e-5f);
    ushort_t* orow = xn + (size_t)row * EDIM;
    orow[t] = f2bf((v0 - mean) * rstd * ln1g[t] + ln1b[t]);
    orow[t + 256] = f2bf((v1 - mean) * rstd * ln1g[t + 256] + ln1b[t + 256]);
    orow[t + 512] = f2bf((v2 - mean) * rstd * ln1g[t + 512] + ln1b[t + 512]);
  } else {
    const int n = (y - 483) * 24 + blockIdx.x; // < 3072 (128*24)
    const int i = n & 3, j = n >> 2;
    const int t = ty * 32 + tx;
    float s = 0.f;
    for (int m = t; m < 768; m += 256)
      s += b1[i + m] * wvqc[(size_t)m * 768 + j];
#pragma unroll
    for (int mm = 32; mm; mm >>= 1) s += __shfl_xor(s, mm);
    const int wid = t >> 6, lane = t & 63;
    if (lane == 0) red[wid] = s;
    __syncthreads();
    if (t == 0) b1e[n] = red[0] + red[1] + red[2] + red[3] + bvqc[j];
  }
}

// ---------- LayerNorm row kernel: bf16 in -> bf16 out ----------
__global__ __launch_bounds__(256) void k_lnb(const ushort_t* __restrict__ x,
                                             const float* __restrict__ gam,
                                             const float* __restrict__ bet,
                                             ushort_t* __restrict__ out) {
  const int row = blockIdx.x, t = threadIdx.x;
  const ushort_t* xr = x + (size_t)row * EDIM;
  float v0 = bf2f(xr[t]), v1 = bf2f(xr[t + 256]), v2 = bf2f(xr[t + 512]);
  float s = v0 + v1 + v2;
  float s2 = v0 * v0 + v1 * v1 + v2 * v2;
#pragma unroll
  for (int m = 32; m; m >>= 1) { s += __shfl_xor(s, m); s2 += __shfl_xor(s2, m); }
  __shared__ float red[8];
  const int wid = t >> 6, lane = t & 63;
  if (lane == 0) { red[wid] = s; red[4 + wid] = s2; }
  __syncthreads();
  s = red[0] + red[1] + red[2] + red[3];
  s2 = red[4] + red[5] + red[6] + red[7];
  float mean = s * (1.f / EDIM);
  float var = s2 * (1.f / EDIM) - mean * mean;
  float rstd = rsqrtf(var + 1e-5f);
  ushort_t* orow = out + (size_t)row * EDIM;
  orow[t] = f2bf((v0 - mean) * rstd * gam[t] + bet[t]);
  orow[t + 256] = f2bf((v1 - mean) * rstd * gam[t + 256] + bet[t + 256]);
  orow[t + 512] = f2bf((v2 - mean) * rstd * gam[t + 512] + bet[t + 512]);
}

// ---------- GEMM, templated BK, T2 swizzled LDS, 32KB double-buffer ----------
// 0: QKV scatter (+bias; V written transposed+psi-permuted as [bh][d][psi(t)])
// 1: f32 out = resid + acc + bias     2: gelu(acc+bias) -> bf16
// 3: W1effT store row*4+z             5: split-K partial -> bf16 buffer z
// 6: bf16 out = resid(f32) + acc + bias
template <int MODE, int BM, int BN, int BK>
__global__ __launch_bounds__(256) void k_gemm(
    const ushort_t* __restrict__ A, const ushort_t* __restrict__ Bt, int lda,
    int ldb, int kc, const float* __restrict__ b0, const float* __restrict__ b1p,
    const float* __restrict__ b2p, float* __restrict__ outF,
    const float* __restrict__ resid, ushort_t* __restrict__ o0,
    ushort_t* __restrict__ o1, ushort_t* __restrict__ o2, int ldc) {
  constexpr int MT = BM / 32, NT = BN / 32; // frags per wave (2x2 wave grid)
  constexpr int KCH = BK / 8;               // 16B chunks per row
  constexpr int NPA = BM * BK / 2048;       // staging passes (4KB each)
  constexpr int NPB = BN * BK / 2048;
  constexpr int ROWSP = 2048 / BK;          // rows per staging pass
  constexpr int KK = BK / 32;
  __shared__ ushort_t As[2][BM * BK];
  __shared__ ushort_t Bs[2][BN * BK];
  const int t = threadIdx.x;
  const int m0 = blockIdx.x * BM, n0 = blockIdx.y * BN;
  if (MODE == 3) Bt += (size_t)blockIdx.z * 768 * 768;
  const int koff = (MODE == 5) ? blockIdx.z * kc : 0;
  const int srow = t / KCH, sch = t % KCH;
  const int xs = (BK == 64) ? (srow & 7) : ((srow >> 1) & 3);
  const int gseg = (sch ^ xs) * 8; // inverse-swizzled global chunk
  const ushort_t* ga = A + (size_t)(m0 + srow) * lda + koff + gseg;
  const ushort_t* gb = Bt + (size_t)(n0 + srow) * ldb + koff + gseg;
  const int ldst = t * 8;
  const int lane = t & 63, wid = t >> 6;
  const int g = lane >> 4, c = lane & 15;
  const int wm = (wid >> 1) * (BM / 2), wn = (wid & 1) * (BN / 2);
  const int xc = (BK == 64) ? (c & 7) : ((c >> 1) & 3);
  f32x4 acc[MT][NT] = {};

#define STAGE(BUF, K0)                                                           \
  {                                                                              \
    _Pragma("unroll") for (int p = 0; p < NPA; p++)                              \
        gload_lds16(ga + (K0) + (size_t)(p * ROWSP) * lda,                       \
                    As[BUF] + p * 2048 + ldst);                                  \
    _Pragma("unroll") for (int p = 0; p < NPB; p++)                              \
        gload_lds16(gb + (K0) + (size_t)(p * ROWSP) * ldb,                       \
                    Bs[BUF] + p * 2048 + ldst);                                  \
  }

  STAGE(0, 0);
  __syncthreads();
  int cur = 0;
  for (int k0 = 0; k0 < kc; k0 += BK) {
    if (k0 + BK < kc) STAGE(cur ^ 1, k0 + BK);
    short8 af[KK][MT], bfr[KK][NT];
#pragma unroll
    for (int kk = 0; kk < KK; kk++) {
#pragma unroll
      for (int mt = 0; mt < MT; mt++)
        af[kk][mt] = *(const short8*)(As[cur] + (wm + mt * 16 + c) * BK +
                                      (((g + kk * 4) ^ xc) * 8));
#pragma unroll
      for (int nt = 0; nt < NT; nt++)
        bfr[kk][nt] = *(const short8*)(Bs[cur] + (wn + nt * 16 + c) * BK +
                                       (((g + kk * 4) ^ xc) * 8));
    }
    __builtin_amdgcn_s_setprio(1);
#pragma unroll
    for (int kk = 0; kk < KK; kk++)
#pragma unroll
      for (int mt = 0; mt < MT; mt++)
#pragma unroll
        for (int nt = 0; nt < NT; nt++)
          acc[mt][nt] = mfma16(af[kk][mt], bfr[kk][nt], acc[mt][nt]);
    __builtin_amdgcn_s_setprio(0);
    __syncthreads();
    cur ^= 1;
  }
#undef STAGE

  if constexpr (MODE == 0) {
#pragma unroll
    for (int mt = 0; mt < MT; mt++) {
#pragma unroll
      for (int nt = 0; nt < NT; nt++) {
        const int row0 = m0 + wm + mt * 16 + g * 4;
        const int col = n0 + wn + nt * 16 + c;
        const int which = col / 768; // block-uniform (BN=64 | 768)
        const int nn = col - which * 768;
        const int h = nn >> 6, d = nn & 63;
        const int bb = row0 >> 11, s0 = row0 & 2047;
        if (which == 2) {
          // V: transposed + psi-permuted store, 4 consecutive tokens -> 8B
          const int tl = s0 & 63;
          const int tp = (s0 & ~63) + 32 * (tl >> 5) + 8 * ((tl >> 2) & 3) +
                         4 * ((tl >> 4) & 1);
          s16x4 pv;
#pragma unroll
          for (int r = 0; r < 4; r++)
            pv[r] = (short)f2bf(acc[mt][nt][r] + b2p[nn]);
          *(s16x4*)(o2 + ((size_t)(bb * 12 + h) * 64 + d) * SDIM + tp) = pv;
        } else {
          const float* bp = which == 0 ? b0 : b1p;
          ushort_t* dp = which == 0 ? o0 : o1;
#pragma unroll
          for (int r = 0; r < 4; r++)
            dp[((size_t)(bb * 12 + h) * SDIM + s0 + r) * 64 + d] =
                f2bf(acc[mt][nt][r] + bp[nn]);
        }
      }
    }
    return;
  }

#pragma unroll
  for (int mt = 0; mt < MT; mt++) {
#pragma unroll
    for (int nt = 0; nt < NT; nt++) {
#pragma unroll
      for (int r = 0; r < 4; r++) {
        int row = m0 + wm + mt * 16 + g * 4 + r;
        int col = n0 + wn + nt * 16 + c;
        float val = acc[mt][nt][r];
        if constexpr (MODE == 1) {
          size_t o = (size_t)row * ldc + col;
          outF[o] = resid[o] + val + b0[col];
        } else if constexpr (MODE == 2) {
          float xg = val + b0[col];
          float z2 = xg * (1.5957691216f + 0.0713548162f * xg * xg);
          float ge = xg / (1.f + __expf(-z2));
          o0[(size_t)row * ldc + col] = f2bf(ge);
        } else if constexpr (MODE == 5) {
          o0[(size_t)blockIdx.z * (NTOK * 768) + (size_t)row * ldc + col] =
              f2bf(val);
        } else if constexpr (MODE == 6) {
          size_t o = (size_t)row * ldc + col;
          o0[o] = f2bf(resid[o] + val + b0[col]);
        } else {
          o0[((size_t)row * 4 + blockIdx.z) * ldc + col] = f2bf(val);
        }
      }
    }
  }
}

// ---------- flash attention v9: 32 q-rows/wave, split-KV x2, inline q-norm ----
__global__ __launch_bounds__(256) void k_attn(
    const ushort_t* __restrict__ q, const ushort_t* __restrict__ k,
    const ushort_t* __restrict__ vt, ushort_t* __restrict__ o0p,
    ushort_t* __restrict__ o1p, float* __restrict__ lpart) {
  const int tid = threadIdx.x;
  const int wid = tid >> 6, lane = tid & 63;
  const int g = lane >> 4, c = lane & 15;
  const int bh = blockIdx.y;
  const int z = blockIdx.z;
  const int tbase = z * (SDIM / 2);
  const int q0 = blockIdx.x * 128 + wid * 32;
  const int bb = bh / 12, h = bh - bb * 12;
  const ushort_t* qb = q + (size_t)bh * SDIM * 64;
  const ushort_t* kb = k + (size_t)bh * SDIM * 64;
  const ushort_t* vb = vt + (size_t)bh * 64 * SDIM;

  __shared__ ushort_t Ks[2][64 * 64]; // linear, swizzled content
  __shared__ ushort_t Vs[2][64 * 64];

  short8 bq[2][2];
#pragma unroll
  for (int qg = 0; qg < 2; qg++) {
    short8 a0 = *(const short8*)(qb + (size_t)(q0 + qg * 16 + c) * 64 + g * 8);
    short8 a1 =
        *(const short8*)(qb + (size_t)(q0 + qg * 16 + c) * 64 + 32 + g * 8);
    float s = 0.f;
#pragma unroll
    for (int j = 0; j < 8; j++) {
      float f0 = bf2f((ushort_t)a0[j]), f1 = bf2f((ushort_t)a1[j]);
      s += f0 * f0 + f1 * f1;
    }
    s += __shfl_xor(s, 16);
    s += __shfl_xor(s, 32);
    const float scq = rsqrtf(64.f * fmaxf(s, 1e-5f)) * 1.44269504089f;
#pragma unroll
    for (int j = 0; j < 8; j++) {
      bq[qg][0][j] = (short)f2bf(bf2f((ushort_t)a0[j]) * scq);
      bq[qg][1][j] = (short)f2bf(bf2f((ushort_t)a1[j]) * scq);
    }
  }
  const short8 ones = {0x3F80, 0x3F80, 0x3F80, 0x3F80,
                       0x3F80, 0x3F80, 0x3F80, 0x3F80}; // bf16 1.0 x8

  const int srow = tid >> 3, sj = tid & 7;

#define STAGE(BUF, T0)                                                          \
  {                                                                             \
    _Pragma("unroll") for (int n = 0; n < 2; n++) {                             \
      const int row = n * 32 + srow;                                            \
      const int scol = (sj ^ (row & 7)) * 8;                                    \
      gload_lds16(kb + (size_t)((T0) + row) * 64 + scol,                        \
                  Ks[BUF] + n * 2048 + tid * 8);                                \
      gload_lds16(vb + (size_t)row * SDIM + (T0) + scol,                        \
                  Vs[BUF] + n * 2048 + tid * 8);                                \
    }                                                                           \
  }

  f32x4 accO[2][4] = {};
  f32x4 accL[2] = {};
  const int sw = (c & 7) << 4;

  STAGE(0, tbase);
  __syncthreads();
  int cur = 0;
  for (int tt = 0; tt < SDIM / 128; tt++) {
    const int t0 = tbase + tt * 64;
    if (tt + 1 < SDIM / 128) STAGE(cur ^ 1, t0 + 64);
    const char* Kc = (const char*)Ks[cur];
    const char* Vc = (const char*)Vs[cur];
    f32x4 s0[4] = {}, s1[4] = {};
    __builtin_amdgcn_s_setprio(1);
#pragma unroll
    for (int i = 0; i < 4; i++) {
      const int rb = (i * 16 + c) * 128;
      short8 ka0 = *(const short8*)(Kc + rb + ((g * 16) ^ sw));
      short8 ka1 = *(const short8*)(Kc + rb + ((64 + g * 16) ^ sw));
      s0[i] = mfma16(ka0, bq[0][0], s0[i]);
      s1[i] = mfma16(ka0, bq[1][0], s1[i]);
      s0[i] = mfma16(ka1, bq[0][1], s0[i]);
      s1[i] = mfma16(ka1, bq[1][1], s1[i]);
    }
    __builtin_amdgcn_s_setprio(0);
    u32x4 w00 = {cvtpk(exp2fast(s0[0][0]), exp2fast(s0[0][1])),
                 cvtpk(exp2fast(s0[0][2]), exp2fast(s0[0][3])),
                 cvtpk(exp2fast(s0[1][0]), exp2fast(s0[1][1])),
                 cvtpk(exp2fast(s0[1][2]), exp2fast(s0[1][3]))};
    u32x4 w10 = {cvtpk(exp2fast(s1[0][0]), exp2fast(s1[0][1])),
                 cvtpk(exp2fast(s1[0][2]), exp2fast(s1[0][3])),
                 cvtpk(exp2fast(s1[1][0]), exp2fast(s1[1][1])),
                 cvtpk(exp2fast(s1[1][2]), exp2fast(s1[1][3]))};
    u32x4 w01 = {cvtpk(exp2fast(s0[2][0]), exp2fast(s0[2][1])),
                 cvtpk(exp2fast(s0[2][2]), exp2fast(s0[2][3])),
                 cvtpk(exp2fast(s0[3][0]), exp2fast(s0[3][1])),
                 cvtpk(exp2fast(s0[3][2]), exp2fast(s0[3][3]))};
    u32x4 w11 = {cvtpk(exp2fast(s1[2][0]), exp2fast(s1[2][1])),
                 cvtpk(exp2fast(s1[2][2]), exp2fast(s1[2][3])),
                 cvtpk(exp2fast(s1[3][0]), exp2fast(s1[3][1])),
                 cvtpk(exp2fast(s1[3][2]), exp2fast(s1[3][3]))};
    short8 pa00 = __builtin_bit_cast(short8, w00);
    short8 pa01 = __builtin_bit_cast(short8, w01);
    short8 pa10 = __builtin_bit_cast(short8, w10);
    short8 pa11 = __builtin_bit_cast(short8, w11);
    __builtin_amdgcn_s_setprio(1);
    accL[0] = mfma16(pa00, ones, accL[0]);
    accL[1] = mfma16(pa10, ones, accL[1]);
    accL[0] = mfma16(pa01, ones, accL[0]);
    accL[1] = mfma16(pa11, ones, accL[1]);
#pragma unroll
    for (int dt = 0; dt < 4; dt++) {
      const int vbse = (dt * 16 + c) * 128;
      short8 v0 = *(const short8*)(Vc + vbse + ((g * 16) ^ sw));
      short8 v1 = *(const short8*)(Vc + vbse + ((64 + g * 16) ^ sw));
      accO[0][dt] = mfma16(pa00, v0, accO[0][dt]);
      accO[1][dt] = mfma16(pa10, v0, accO[1][dt]);
      accO[0][dt] = mfma16(pa01, v1, accO[0][dt]);
      accO[1][dt] = mfma16(pa11, v1, accO[1][dt]);
    }
    __builtin_amdgcn_s_setprio(0);
    __syncthreads();
    cur ^= 1;
  }
#undef STAGE

  ushort_t* op = z ? o1p : o0p;
#pragma unroll
  for (int qg = 0; qg < 2; qg++) {
    if (c == 0) {
#pragma unroll
      for (int r = 0; r < 4; r++)
        lpart[((size_t)z * 24 + bh) * SDIM + q0 + qg * 16 + 4 * g + r] =
            accL[qg][r];
    }
#pragma unroll
    for (int dt = 0; dt < 4; dt++)
#pragma unroll
      for (int r = 0; r < 4; r++) {
        int s = q0 + qg * 16 + 4 * g + r;
        op[((size_t)(bb * SDIM + s)) * EDIM + h * 64 + dt * 16 + c] =
            f2bf(accO[qg][dt][r]);
      }
  }
}

// ---------- combine split-KV partials: vals = (O0+O1)/(l0+l1) ----------
__global__ __launch_bounds__(256) void k_comb(const ushort_t* __restrict__ o0p,
                                              const ushort_t* __restrict__ o1p,
                                              const float* __restrict__ lpart,
                                              ushort_t* __restrict__ vals) {
  const int gid = blockIdx.x * 256 + threadIdx.x; // < 4096*96
  const int tok = gid / 96, ch = gid - tok * 96;
  const int h = ch >> 3;
  const int bb = tok >> 11, s = tok & 2047;
  const size_t lrow = (size_t)(bb * 12 + h) * SDIM + s;
  const float inv = 1.f / (lpart[lrow] + lpart[(size_t)24 * SDIM + lrow]);
  short8 a = *(const short8*)(o0p + (size_t)gid * 8);
  short8 b = *(const short8*)(o1p + (size_t)gid * 8);
  short8 o;
#pragma unroll
  for (int j = 0; j < 8; j++)
    o[j] = (short)f2bf((bf2f((ushort_t)a[j]) + bf2f((ushort_t)b[j])) * inv);
  *(short8*)(vals + (size_t)gid * 8) = o;
}

// ---------- final: out = x2(bf16) + b2 + p0 + p1 (MLP2 split-K combine) ------
__global__ __launch_bounds__(256) void k_fin(const ushort_t* __restrict__ x2b,
                                             const float* __restrict__ b2,
                                             const ushort_t* __restrict__ p,
                                             float* __restrict__ out) {
  const int i = blockIdx.x * 256 + threadIdx.x; // < 786432 (f32x4 groups)
  s16x4 rx = ((const s16x4*)x2b)[i];
  f32x4 b = ((const f32x4*)b2)[i % 192];
  s16x4 a0 = ((const s16x4*)p)[i];
  s16x4 a1 = ((const s16x4*)(p + (size_t)NTOK * 768))[i];
  f32x4 o;
#pragma unroll
  for (int j = 0; j < 4; j++)
    o[j] = bf2f((ushort_t)rx[j]) + b[j] + bf2f((ushort_t)a0[j]) +
           bf2f((ushort_t)a1[j]);
  ((f32x4*)out)[i] = o;
}

extern "C" void kernel_launch(void* const* d_in, const int* in_sizes, int n_in,
                              void* d_out, int out_size, void* d_ws, size_t ws_size,
                              hipStream_t stream) {
  const float* x = (const float*)d_in[0];
  const float* ln1g = (const float*)d_in[1];
  const float* ln1b = (const float*)d_in[2];
  const float* wq = (const float*)d_in[3];
  const float* bq = (const float*)d_in[4];
  const float* wk = (const float*)d_in[5];
  const float* bk = (const float*)d_in[6];
  const float* wv = (const float*)d_in[7];
  const float* bv = (const float*)d_in[8];
  const float* wo = (const float*)d_in[9];
  const float* bo = (const float*)d_in[10];
  const float* ln2g = (const float*)d_in[11];
  const float* ln2b = (const float*)d_in[12];
  const float* w1 = (const float*)d_in[13];
  const float* b1 = (const float*)d_in[14];
  const float* wvqc = (const float*)d_in[15];
  const float* bvqc = (const float*)d_in[16];
  const float* w2 = (const float*)d_in[17];
  const float* b2 = (const float*)d_in[18];
  float* out = (float*)d_out;

  char* w = (char*)d_ws;
  ushort_t* xn = (ushort_t*)(w + 0);           // 6291456 (dead after QKV gemm)
  ushort_t* xn2 = (ushort_t*)(w + 6291456);    // 6291456; Opart1 before LN2
  ushort_t* opart1 = (ushort_t*)(w + 6291456);
  ushort_t* x2b = (ushort_t*)(w + 12582912);   // bf16 residual, 6291456
  ushort_t* qb = (ushort_t*)(w + 25165824);    // 6291456
  ushort_t* kb = (ushort_t*)(w + 31457280);    // 6291456
  ushort_t* vb = (ushort_t*)(w + 37748736);    // 6291456 (V^T psi layout)
  ushort_t* vals = (ushort_t*)(w + 44040192);  // 6291456; Opart0 (in-place comb)
  ushort_t* G = (ushort_t*)(w + 25165824);     // overlays q..vals
  ushort_t* wqkvT = (ushort_t*)(w + 50528256); // 3538944
  ushort_t* woT = (ushort_t*)(w + 54067200);   // 1179648
  ushort_t* wvqcT = (ushort_t*)(w + 55246848); // 1179648
  ushort_t* w1s = (ushort_t*)(w + 56426496);   // 4718592; lpart after W1eff gemm
  float* lpart = (float*)(w + 56426496);       // 393216 (dead w1s)
  ushort_t* W1eT = (ushort_t*)(w + 61145088);  // 4718592
  float* b1e = (float*)(w + 65863680);         // 12288
  ushort_t* w2T = (ushort_t*)(w + 65875968);   // 4718592 -> end 70594560
  ushort_t* mp = (ushort_t*)(w + 0); // MLP2 partials [2][4096*768] bf16

  dim3 tb(32, 8);
  // merged preprocessing: weight transposes + w1 shifts + LN1 + b1eff
  k_pre<<<dim3(24, 611), tb, 0, stream>>>(wq, wk, wv, wo, wvqc, w2, w1, x, ln1g,
                                          ln1b, b1, bvqc, wqkvT, woT, wvqcT, w2T,
                                          w1s, xn, b1e);
  // W1effT[j*4+i][e] = sum_m wvqcT[j][m] * w1s[i][e][m]
  k_gemm<3, 64, 64, 64><<<dim3(12, 12, 4), 256, 0, stream>>>(
      wvqcT, w1s, 768, 768, 768, nullptr, nullptr, nullptr, nullptr, nullptr,
      W1eT, nullptr, nullptr, 768);
  // QKV: V written directly as V^T psi-permuted (k_vT fused away)
  k_gemm<0, 128, 64, 64><<<dim3(32, 36), 256, 0, stream>>>(
      xn, wqkvT, 768, 768, 768, bq, bk, bv, nullptr, nullptr, qb, kb, vb, 0);
  // xn dead from here. w1s dead; lpart overlays it.
  k_attn<<<dim3(16, 24, 2), 256, 0, stream>>>(qb, kb, vb, vals, opart1, lpart);
  k_comb<<<1536, 256, 0, stream>>>(vals, opart1, lpart, vals);
  // x2b = bf16(x + vals @ woT + bo)  (MODE 6)
  k_gemm<6, 64, 64, 64><<<dim3(64, 12), 256, 0, stream>>>(
      vals, woT, 768, 768, 768, bo, nullptr, nullptr, nullptr, x, x2b, nullptr,
      nullptr, 768);
  k_lnb<<<4096, 256, 0, stream>>>(x2b, ln2g, ln2b, xn2);
  k_gemm<2, 128, 64, 64><<<dim3(32, 48), 256, 0, stream>>>(
      xn2, W1eT, 768, 768, 768, b1e, nullptr, nullptr, nullptr, nullptr, G,
      nullptr, nullptr, 3072);
  // MLP2 split-K=2: bf16 partials (direct store) then combine with resid+bias
  k_gemm<5, 64, 64, 64><<<dim3(64, 12, 2), 256, 0, stream>>>(
      G, w2T, 3072, 3072, 1536, nullptr, nullptr, nullptr, nullptr, nullptr, mp,
      nullptr, nullptr, 768);
  k_fin<<<3072, 256, 0, stream>>>(x2b, b2, mp, out);
}

// Round 24
// 190.450 us; speedup vs baseline: 1.0152x; 1.0152x over previous
//
#include <hip/hip_runtime.h>
#include <hip/hip_bf16.h>
#include <math.h>

typedef unsigned short ushort_t; // bf16 bits
typedef __attribute__((ext_vector_type(4))) short s16x4;
typedef __attribute__((ext_vector_type(8))) short short8;
typedef __attribute__((ext_vector_type(8))) __bf16 bf16x8;
typedef __attribute__((ext_vector_type(4))) float f32x4;
typedef __attribute__((ext_vector_type(4))) unsigned u32x4;

#define SDIM 2048
#define EDIM 768
#define NTOK 4096

static __device__ __forceinline__ ushort_t f2bf(float f) {
  unsigned u = __builtin_bit_cast(unsigned, f);
  u += 0x7fff + ((u >> 16) & 1);
  return (ushort_t)(u >> 16);
}
static __device__ __forceinline__ float bf2f(ushort_t h) {
  return __builtin_bit_cast(float, (unsigned)h << 16);
}
static __device__ __forceinline__ f32x4 mfma16(short8 a, short8 b, f32x4 c) {
  return __builtin_amdgcn_mfma_f32_16x16x32_bf16(
      __builtin_bit_cast(bf16x8, a), __builtin_bit_cast(bf16x8, b), c, 0, 0, 0);
}
static __device__ __forceinline__ void gload_lds16(const void* g, void* l) {
  __builtin_amdgcn_global_load_lds(
      (const __attribute__((address_space(1))) void*)g,
      (__attribute__((address_space(3))) void*)l, 16, 0, 0);
}
static __device__ __forceinline__ unsigned cvtpk(float lo, float hi) {
  unsigned r;
  asm("v_cvt_pk_bf16_f32 %0, %1, %2" : "=v"(r) : "v"(lo), "v"(hi));
  return r;
}
static __device__ __forceinline__ float exp2fast(float x) {
  float r;
  asm("v_exp_f32 %0, %1" : "=v"(r) : "v"(x));
  return r;
}

// ---------- merged preprocessing ----------
// grid (24, 483), block (32,8):
//   y in [0,120): five 768x768 cast+transpose jobs (y/24 selects weight)
//   y in [120,216): w2 [3072][768] -> w2T [768][3072]
//   y in [216,312): w1 shifted copies w1s[i][e][m] = w1[e][i+m]
//   y in [312,483): LayerNorm1 rows (row = (y-312)*24 + blockIdx.x)
__global__ void k_pre(const float* __restrict__ wq, const float* __restrict__ wk,
                      const float* __restrict__ wv, const float* __restrict__ wo,
                      const float* __restrict__ wvqc, const float* __restrict__ w2,
                      const float* __restrict__ w1, const float* __restrict__ x,
                      const float* __restrict__ ln1g, const float* __restrict__ ln1b,
                      ushort_t* __restrict__ oqkv, ushort_t* __restrict__ owo,
                      ushort_t* __restrict__ ovqc, ushort_t* __restrict__ w2T,
                      ushort_t* __restrict__ w1s, ushort_t* __restrict__ xn) {
  const int y = blockIdx.y;
  const int tx = threadIdx.x, ty = threadIdx.y;
  __shared__ float tile[32][33];
  __shared__ float red[8];
  if (y < 216) {
    const float* in;
    ushort_t* out;
    int R, r0;
    const int c0 = blockIdx.x * 32;
    if (y < 120) {
      const int z = y / 24, ry = y - z * 24;
      in = z == 0 ? wq : z == 1 ? wk : z == 2 ? wv : z == 3 ? wo : wvqc;
      out = z < 3 ? oqkv + (size_t)z * 768 * 768 : (z == 3 ? owo : ovqc);
      R = 768;
      r0 = ry * 32;
    } else {
      in = w2;
      out = w2T;
      R = 3072;
      r0 = (y - 120) * 32;
    }
#pragma unroll
    for (int i = 0; i < 32; i += 8)
      tile[ty + i][tx] = in[(size_t)(r0 + ty + i) * 768 + c0 + tx];
    __syncthreads();
#pragma unroll
    for (int i = 0; i < 32; i += 8)
      out[(size_t)(c0 + ty + i) * R + r0 + tx] = f2bf(tile[tx][ty + i]);
  } else if (y < 312) {
    const int idx = ((y - 216) * 24 + blockIdx.x) * 256 + ty * 32 + tx;
    const int e = idx / 768, m = idx - (idx / 768) * 768;
#pragma unroll
    for (int i = 0; i < 4; i++)
      w1s[((size_t)i * 768 + e) * 768 + m] = f2bf(w1[(size_t)e * 3072 + i + m]);
  } else {
    const int row = (y - 312) * 24 + blockIdx.x;
    if (row >= NTOK) return;
    const int t = ty * 32 + tx;
    const float* xr = x + (size_t)row * EDIM;
    float v0 = xr[t], v1 = xr[t + 256], v2 = xr[t + 512];
    float s = v0 + v1 + v2;
    float s2 = v0 * v0 + v1 * v1 + v2 * v2;
#pragma unroll
    for (int m = 32; m; m >>= 1) {
      s += __shfl_xor(s, m);
      s2 += __shfl_xor(s2, m);
    }
    const int wid = t >> 6, lane = t & 63;
    if (lane == 0) { red[wid] = s; red[4 + wid] = s2; }
    __syncthreads();
    s = red[0] + red[1] + red[2] + red[3];
    s2 = red[4] + red[5] + red[6] + red[7];
    float mean = s * (1.f / EDIM);
    float var = s2 * (1.f / EDIM) - mean * mean;
    float rstd = rsqrtf(var + 1e-5f);
    ushort_t* orow = xn + (size_t)row * EDIM;
    orow[t] = f2bf((v0 - mean) * rstd * ln1g[t] + ln1b[t]);
    orow[t + 256] = f2bf((v1 - mean) * rstd * ln1g[t + 256] + ln1b[t + 256]);
    orow[t + 512] = f2bf((v2 - mean) * rstd * ln1g[t + 512] + ln1b[t + 512]);
  }
}

// ---------- b1eff[n] = sum_m b1[i+m]*wvqc[m][j] + bvqc[j], n=j*4+i ----------
__global__ __launch_bounds__(256) void k_b1eff(const float* __restrict__ b1,
                                               const ushort_t* __restrict__ wvqcT,
                                               const float* __restrict__ bvqc,
                                               float* __restrict__ b1e) {
  const int n = blockIdx.x; // 3072
  const int i = n & 3, j = n >> 2;
  const int t = threadIdx.x;
  float s = 0.f;
  for (int m = t; m < 768; m += 256)
    s += b1[i + m] * bf2f(wvqcT[(size_t)j * 768 + m]);
#pragma unroll
  for (int mm = 32; mm; mm >>= 1) s += __shfl_xor(s, mm);
  __shared__ float red[4];
  if ((t & 63) == 0) red[t >> 6] = s;
  __syncthreads();
  if (t == 0) b1e[n] = red[0] + red[1] + red[2] + red[3] + bvqc[j];
}

// ---------- LayerNorm row kernel: bf16 in -> bf16 out ----------
__global__ __launch_bounds__(256) void k_lnb(const ushort_t* __restrict__ x,
                                             const float* __restrict__ gam,
                                             const float* __restrict__ bet,
                                             ushort_t* __restrict__ out) {
  const int row = blockIdx.x, t = threadIdx.x;
  const ushort_t* xr = x + (size_t)row * EDIM;
  float v0 = bf2f(xr[t]), v1 = bf2f(xr[t + 256]), v2 = bf2f(xr[t + 512]);
  float s = v0 + v1 + v2;
  float s2 = v0 * v0 + v1 * v1 + v2 * v2;
#pragma unroll
  for (int m = 32; m; m >>= 1) { s += __shfl_xor(s, m); s2 += __shfl_xor(s2, m); }
  __shared__ float red[8];
  const int wid = t >> 6, lane = t & 63;
  if (lane == 0) { red[wid] = s; red[4 + wid] = s2; }
  __syncthreads();
  s = red[0] + red[1] + red[2] + red[3];
  s2 = red[4] + red[5] + red[6] + red[7];
  float mean = s * (1.f / EDIM);
  float var = s2 * (1.f / EDIM) - mean * mean;
  float rstd = rsqrtf(var + 1e-5f);
  ushort_t* orow = out + (size_t)row * EDIM;
  orow[t] = f2bf((v0 - mean) * rstd * gam[t] + bet[t]);
  orow[t + 256] = f2bf((v1 - mean) * rstd * gam[t + 256] + bet[t + 256]);
  orow[t + 512] = f2bf((v2 - mean) * rstd * gam[t + 512] + bet[t + 512]);
}

// ---------- GEMM, templated BK, T2 swizzled LDS, 32KB double-buffer ----------
// 0: QKV scatter (+bias; V written transposed+psi-permuted as [bh][d][psi(t)])
// 1: f32 out = resid + acc + bias     2: gelu(acc+bias) -> bf16
// 3: W1effT store row*4+z             5: split-K partial -> bf16 buffer z
// 6: bf16 out = resid(f32) + acc + bias
template <int MODE, int BM, int BN, int BK>
__global__ __launch_bounds__(256) void k_gemm(
    const ushort_t* __restrict__ A, const ushort_t* __restrict__ Bt, int lda,
    int ldb, int kc, const float* __restrict__ b0, const float* __restrict__ b1p,
    const float* __restrict__ b2p, float* __restrict__ outF,
    const float* __restrict__ resid, ushort_t* __restrict__ o0,
    ushort_t* __restrict__ o1, ushort_t* __restrict__ o2, int ldc) {
  constexpr int MT = BM / 32, NT = BN / 32; // frags per wave (2x2 wave grid)
  constexpr int KCH = BK / 8;               // 16B chunks per row
  constexpr int NPA = BM * BK / 2048;       // staging passes (4KB each)
  constexpr int NPB = BN * BK / 2048;
  constexpr int ROWSP = 2048 / BK;          // rows per staging pass
  constexpr int KK = BK / 32;
  __shared__ ushort_t As[2][BM * BK];
  __shared__ ushort_t Bs[2][BN * BK];
  const int t = threadIdx.x;
  const int m0 = blockIdx.x * BM, n0 = blockIdx.y * BN;
  if (MODE == 3) Bt += (size_t)blockIdx.z * 768 * 768;
  const int koff = (MODE == 5) ? blockIdx.z * kc : 0;
  const int srow = t / KCH, sch = t % KCH;
  const int xs = (BK == 64) ? (srow & 7) : ((srow >> 1) & 3);
  const int gseg = (sch ^ xs) * 8; // inverse-swizzled global chunk
  const ushort_t* ga = A + (size_t)(m0 + srow) * lda + koff + gseg;
  const ushort_t* gb = Bt + (size_t)(n0 + srow) * ldb + koff + gseg;
  const int ldst = t * 8;
  const int lane = t & 63, wid = t >> 6;
  const int g = lane >> 4, c = lane & 15;
  const int wm = (wid >> 1) * (BM / 2), wn = (wid & 1) * (BN / 2);
  const int xc = (BK == 64) ? (c & 7) : ((c >> 1) & 3);
  f32x4 acc[MT][NT] = {};

#define STAGE(BUF, K0)                                                           \
  {                                                                              \
    _Pragma("unroll") for (int p = 0; p < NPA; p++)                              \
        gload_lds16(ga + (K0) + (size_t)(p * ROWSP) * lda,                       \
                    As[BUF] + p * 2048 + ldst);                                  \
    _Pragma("unroll") for (int p = 0; p < NPB; p++)                              \
        gload_lds16(gb + (K0) + (size_t)(p * ROWSP) * ldb,                       \
                    Bs[BUF] + p * 2048 + ldst);                                  \
  }

  STAGE(0, 0);
  __syncthreads();
  int cur = 0;
  for (int k0 = 0; k0 < kc; k0 += BK) {
    if (k0 + BK < kc) STAGE(cur ^ 1, k0 + BK);
    short8 af[KK][MT], bfr[KK][NT];
#pragma unroll
    for (int kk = 0; kk < KK; kk++) {
#pragma unroll
      for (int mt = 0; mt < MT; mt++)
        af[kk][mt] = *(const short8*)(As[cur] + (wm + mt * 16 + c) * BK +
                                      (((g + kk * 4) ^ xc) * 8));
#pragma unroll
      for (int nt = 0; nt < NT; nt++)
        bfr[kk][nt] = *(const short8*)(Bs[cur] + (wn + nt * 16 + c) * BK +
                                       (((g + kk * 4) ^ xc) * 8));
    }
    __builtin_amdgcn_s_setprio(1);
#pragma unroll
    for (int kk = 0; kk < KK; kk++)
#pragma unroll
      for (int mt = 0; mt < MT; mt++)
#pragma unroll
        for (int nt = 0; nt < NT; nt++)
          acc[mt][nt] = mfma16(af[kk][mt], bfr[kk][nt], acc[mt][nt]);
    __builtin_amdgcn_s_setprio(0);
    __syncthreads();
    cur ^= 1;
  }
#undef STAGE

  if constexpr (MODE == 0) {
#pragma unroll
    for (int mt = 0; mt < MT; mt++) {
#pragma unroll
      for (int nt = 0; nt < NT; nt++) {
        const int row0 = m0 + wm + mt * 16 + g * 4;
        const int col = n0 + wn + nt * 16 + c;
        const int which = col / 768; // block-uniform (BN=64 | 768)
        const int nn = col - which * 768;
        const int h = nn >> 6, d = nn & 63;
        const int bb = row0 >> 11, s0 = row0 & 2047;
        if (which == 2) {
          // V: transposed + psi-permuted store, 4 consecutive tokens -> 8B
          const int tl = s0 & 63;
          const int tp = (s0 & ~63) + 32 * (tl >> 5) + 8 * ((tl >> 2) & 3) +
                         4 * ((tl >> 4) & 1);
          s16x4 pv;
#pragma unroll
          for (int r = 0; r < 4; r++)
            pv[r] = (short)f2bf(acc[mt][nt][r] + b2p[nn]);
          *(s16x4*)(o2 + ((size_t)(bb * 12 + h) * 64 + d) * SDIM + tp) = pv;
        } else {
          const float* bp = which == 0 ? b0 : b1p;
          ushort_t* dp = which == 0 ? o0 : o1;
#pragma unroll
          for (int r = 0; r < 4; r++)
            dp[((size_t)(bb * 12 + h) * SDIM + s0 + r) * 64 + d] =
                f2bf(acc[mt][nt][r] + bp[nn]);
        }
      }
    }
    return;
  }

#pragma unroll
  for (int mt = 0; mt < MT; mt++) {
#pragma unroll
    for (int nt = 0; nt < NT; nt++) {
#pragma unroll
      for (int r = 0; r < 4; r++) {
        int row = m0 + wm + mt * 16 + g * 4 + r;
        int col = n0 + wn + nt * 16 + c;
        float val = acc[mt][nt][r];
        if constexpr (MODE == 1) {
          size_t o = (size_t)row * ldc + col;
          outF[o] = resid[o] + val + b0[col];
        } else if constexpr (MODE == 2) {
          float xg = val + b0[col];
          float z2 = xg * (1.5957691216f + 0.0713548162f * xg * xg);
          float ge = xg / (1.f + __expf(-z2));
          o0[(size_t)row * ldc + col] = f2bf(ge);
        } else if constexpr (MODE == 5) {
          o0[(size_t)blockIdx.z * (NTOK * 768) + (size_t)row * ldc + col] =
              f2bf(val);
        } else if constexpr (MODE == 6) {
          size_t o = (size_t)row * ldc + col;
          o0[o] = f2bf(resid[o] + val + b0[col]);
        } else {
          o0[((size_t)row * 4 + blockIdx.z) * ldc + col] = f2bf(val);
        }
      }
    }
  }
}

// ---------- flash attention v9: 32 q-rows/wave, split-KV x2, inline q-norm ----
__global__ __launch_bounds__(256) void k_attn(
    const ushort_t* __restrict__ q, const ushort_t* __restrict__ k,
    const ushort_t* __restrict__ vt, ushort_t* __restrict__ o0p,
    ushort_t* __restrict__ o1p, float* __restrict__ lpart) {
  const int tid = threadIdx.x;
  const int wid = tid >> 6, lane = tid & 63;
  const int g = lane >> 4, c = lane & 15;
  const int bh = blockIdx.y;
  const int z = blockIdx.z;
  const int tbase = z * (SDIM / 2);
  const int q0 = blockIdx.x * 128 + wid * 32;
  const int bb = bh / 12, h = bh - bb * 12;
  const ushort_t* qb = q + (size_t)bh * SDIM * 64;
  const ushort_t* kb = k + (size_t)bh * SDIM * 64;
  const ushort_t* vb = vt + (size_t)bh * 64 * SDIM;

  __shared__ ushort_t Ks[2][64 * 64]; // linear, swizzled content
  __shared__ ushort_t Vs[2][64 * 64];

  short8 bq[2][2];
#pragma unroll
  for (int qg = 0; qg < 2; qg++) {
    short8 a0 = *(const short8*)(qb + (size_t)(q0 + qg * 16 + c) * 64 + g * 8);
    short8 a1 =
        *(const short8*)(qb + (size_t)(q0 + qg * 16 + c) * 64 + 32 + g * 8);
    float s = 0.f;
#pragma unroll
    for (int j = 0; j < 8; j++) {
      float f0 = bf2f((ushort_t)a0[j]), f1 = bf2f((ushort_t)a1[j]);
      s += f0 * f0 + f1 * f1;
    }
    s += __shfl_xor(s, 16);
    s += __shfl_xor(s, 32);
    const float scq = rsqrtf(64.f * fmaxf(s, 1e-5f)) * 1.44269504089f;
#pragma unroll
    for (int j = 0; j < 8; j++) {
      bq[qg][0][j] = (short)f2bf(bf2f((ushort_t)a0[j]) * scq);
      bq[qg][1][j] = (short)f2bf(bf2f((ushort_t)a1[j]) * scq);
    }
  }
  const short8 ones = {0x3F80, 0x3F80, 0x3F80, 0x3F80,
                       0x3F80, 0x3F80, 0x3F80, 0x3F80}; // bf16 1.0 x8

  const int srow = tid >> 3, sj = tid & 7;

#define STAGE(BUF, T0)                                                          \
  {                                                                             \
    _Pragma("unroll") for (int n = 0; n < 2; n++) {                             \
      const int row = n * 32 + srow;                                            \
      const int scol = (sj ^ (row & 7)) * 8;                                    \
      gload_lds16(kb + (size_t)((T0) + row) * 64 + scol,                        \
                  Ks[BUF] + n * 2048 + tid * 8);                                \
      gload_lds16(vb + (size_t)row * SDIM + (T0) + scol,                        \
                  Vs[BUF] + n * 2048 + tid * 8);                                \
    }                                                                           \
  }

  f32x4 accO[2][4] = {};
  f32x4 accL[2] = {};
  const int sw = (c & 7) << 4;

  STAGE(0, tbase);
  __syncthreads();
  int cur = 0;
  for (int tt = 0; tt < SDIM / 128; tt++) {
    const int t0 = tbase + tt * 64;
    if (tt + 1 < SDIM / 128) STAGE(cur ^ 1, t0 + 64);
    const char* Kc = (const char*)Ks[cur];
    const char* Vc = (const char*)Vs[cur];
    f32x4 s0[4] = {}, s1[4] = {};
    __builtin_amdgcn_s_setprio(1);
#pragma unroll
    for (int i = 0; i < 4; i++) {
      const int rb = (i * 16 + c) * 128;
      short8 ka0 = *(const short8*)(Kc + rb + ((g * 16) ^ sw));
      short8 ka1 = *(const short8*)(Kc + rb + ((64 + g * 16) ^ sw));
      s0[i] = mfma16(ka0, bq[0][0], s0[i]);
      s1[i] = mfma16(ka0, bq[1][0], s1[i]);
      s0[i] = mfma16(ka1, bq[0][1], s0[i]);
      s1[i] = mfma16(ka1, bq[1][1], s1[i]);
    }
    __builtin_amdgcn_s_setprio(0);
    u32x4 w00 = {cvtpk(exp2fast(s0[0][0]), exp2fast(s0[0][1])),
                 cvtpk(exp2fast(s0[0][2]), exp2fast(s0[0][3])),
                 cvtpk(exp2fast(s0[1][0]), exp2fast(s0[1][1])),
                 cvtpk(exp2fast(s0[1][2]), exp2fast(s0[1][3]))};
    u32x4 w10 = {cvtpk(exp2fast(s1[0][0]), exp2fast(s1[0][1])),
                 cvtpk(exp2fast(s1[0][2]), exp2fast(s1[0][3])),
                 cvtpk(exp2fast(s1[1][0]), exp2fast(s1[1][1])),
                 cvtpk(exp2fast(s1[1][2]), exp2fast(s1[1][3]))};
    u32x4 w01 = {cvtpk(exp2fast(s0[2][0]), exp2fast(s0[2][1])),
                 cvtpk(exp2fast(s0[2][2]), exp2fast(s0[2][3])),
                 cvtpk(exp2fast(s0[3][0]), exp2fast(s0[3][1])),
                 cvtpk(exp2fast(s0[3][2]), exp2fast(s0[3][3]))};
    u32x4 w11 = {cvtpk(exp2fast(s1[2][0]), exp2fast(s1[2][1])),
                 cvtpk(exp2fast(s1[2][2]), exp2fast(s1[2][3])),
                 cvtpk(exp2fast(s1[3][0]), exp2fast(s1[3][1])),
                 cvtpk(exp2fast(s1[3][2]), exp2fast(s1[3][3]))};
    short8 pa00 = __builtin_bit_cast(short8, w00);
    short8 pa01 = __builtin_bit_cast(short8, w01);
    short8 pa10 = __builtin_bit_cast(short8, w10);
    short8 pa11 = __builtin_bit_cast(short8, w11);
    __builtin_amdgcn_s_setprio(1);
    accL[0] = mfma16(pa00, ones, accL[0]);
    accL[1] = mfma16(pa10, ones, accL[1]);
    accL[0] = mfma16(pa01, ones, accL[0]);
    accL[1] = mfma16(pa11, ones, accL[1]);
#pragma unroll
    for (int dt = 0; dt < 4; dt++) {
      const int vbse = (dt * 16 + c) * 128;
      short8 v0 = *(const short8*)(Vc + vbse + ((g * 16) ^ sw));
      short8 v1 = *(const short8*)(Vc + vbse + ((64 + g * 16) ^ sw));
      accO[0][dt] = mfma16(pa00, v0, accO[0][dt]);
      accO[1][dt] = mfma16(pa10, v0, accO[1][dt]);
      accO[0][dt] = mfma16(pa01, v1, accO[0][dt]);
      accO[1][dt] = mfma16(pa11, v1, accO[1][dt]);
    }
    __builtin_amdgcn_s_setprio(0);
    __syncthreads();
    cur ^= 1;
  }
#undef STAGE

  ushort_t* op = z ? o1p : o0p;
#pragma unroll
  for (int qg = 0; qg < 2; qg++) {
    if (c == 0) {
#pragma unroll
      for (int r = 0; r < 4; r++)
        lpart[((size_t)z * 24 + bh) * SDIM + q0 + qg * 16 + 4 * g + r] =
            accL[qg][r];
    }
#pragma unroll
    for (int dt = 0; dt < 4; dt++)
#pragma unroll
      for (int r = 0; r < 4; r++) {
        int s = q0 + qg * 16 + 4 * g + r;
        op[((size_t)(bb * SDIM + s)) * EDIM + h * 64 + dt * 16 + c] =
            f2bf(accO[qg][dt][r]);
      }
  }
}

// ---------- combine split-KV partials: vals = (O0+O1)/(l0+l1) ----------
__global__ __launch_bounds__(256) void k_comb(const ushort_t* __restrict__ o0p,
                                              const ushort_t* __restrict__ o1p,
                                              const float* __restrict__ lpart,
                                              ushort_t* __restrict__ vals) {
  const int gid = blockIdx.x * 256 + threadIdx.x; // < 4096*96
  const int tok = gid / 96, ch = gid - tok * 96;
  const int h = ch >> 3;
  const int bb = tok >> 11, s = tok & 2047;
  const size_t lrow = (size_t)(bb * 12 + h) * SDIM + s;
  const float inv = 1.f / (lpart[lrow] + lpart[(size_t)24 * SDIM + lrow]);
  short8 a = *(const short8*)(o0p + (size_t)gid * 8);
  short8 b = *(const short8*)(o1p + (size_t)gid * 8);
  short8 o;
#pragma unroll
  for (int j = 0; j < 8; j++)
    o[j] = (short)f2bf((bf2f((ushort_t)a[j]) + bf2f((ushort_t)b[j])) * inv);
  *(short8*)(vals + (size_t)gid * 8) = o;
}

// ---------- final: out = x2(bf16) + b2 + p0 + p1 (MLP2 split-K combine) ------
__global__ __launch_bounds__(256) void k_fin(const ushort_t* __restrict__ x2b,
                                             const float* __restrict__ b2,
                                             const ushort_t* __restrict__ p,
                                             float* __restrict__ out) {
  const int i = blockIdx.x * 256 + threadIdx.x; // < 786432 (f32x4 groups)
  s16x4 rx = ((const s16x4*)x2b)[i];
  f32x4 b = ((const f32x4*)b2)[i % 192];
  s16x4 a0 = ((const s16x4*)p)[i];
  s16x4 a1 = ((const s16x4*)(p + (size_t)NTOK * 768))[i];
  f32x4 o;
#pragma unroll
  for (int j = 0; j < 4; j++)
    o[j] = bf2f((ushort_t)rx[j]) + b[j] + bf2f((ushort_t)a0[j]) +
           bf2f((ushort_t)a1[j]);
  ((f32x4*)out)[i] = o;
}

extern "C" void kernel_launch(void* const* d_in, const int* in_sizes, int n_in,
                              void* d_out, int out_size, void* d_ws, size_t ws_size,
                              hipStream_t stream) {
  const float* x = (const float*)d_in[0];
  const float* ln1g = (const float*)d_in[1];
  const float* ln1b = (const float*)d_in[2];
  const float* wq = (const float*)d_in[3];
  const float* bq = (const float*)d_in[4];
  const float* wk = (const float*)d_in[5];
  const float* bk = (const float*)d_in[6];
  const float* wv = (const float*)d_in[7];
  const float* bv = (const float*)d_in[8];
  const float* wo = (const float*)d_in[9];
  const float* bo = (const float*)d_in[10];
  const float* ln2g = (const float*)d_in[11];
  const float* ln2b = (const float*)d_in[12];
  const float* w1 = (const float*)d_in[13];
  const float* b1 = (const float*)d_in[14];
  const float* wvqc = (const float*)d_in[15];
  const float* bvqc = (const float*)d_in[16];
  const float* w2 = (const float*)d_in[17];
  const float* b2 = (const float*)d_in[18];
  float* out = (float*)d_out;

  char* w = (char*)d_ws;
  ushort_t* xn = (ushort_t*)(w + 0);           // 6291456 (dead after QKV gemm)
  ushort_t* xn2 = (ushort_t*)(w + 6291456);    // 6291456; Opart1 before LN2
  ushort_t* opart1 = (ushort_t*)(w + 6291456);
  ushort_t* x2b = (ushort_t*)(w + 12582912);   // bf16 residual, 6291456
  ushort_t* qb = (ushort_t*)(w + 25165824);    // 6291456
  ushort_t* kb = (ushort_t*)(w + 31457280);    // 6291456
  ushort_t* vb = (ushort_t*)(w + 37748736);    // 6291456 (V^T psi layout)
  ushort_t* vals = (ushort_t*)(w + 44040192);  // 6291456; Opart0 (in-place comb)
  ushort_t* G = (ushort_t*)(w + 25165824);     // overlays q..vals
  ushort_t* wqkvT = (ushort_t*)(w + 50528256); // 3538944
  ushort_t* woT = (ushort_t*)(w + 54067200);   // 1179648
  ushort_t* wvqcT = (ushort_t*)(w + 55246848); // 1179648
  ushort_t* w1s = (ushort_t*)(w + 56426496);   // 4718592; lpart after W1eff gemm
  float* lpart = (float*)(w + 56426496);       // 393216 (dead w1s)
  ushort_t* W1eT = (ushort_t*)(w + 61145088);  // 4718592
  float* b1e = (float*)(w + 65863680);         // 12288
  ushort_t* w2T = (ushort_t*)(w + 65875968);   // 4718592 -> end 70594560
  ushort_t* mp = (ushort_t*)(w + 0); // MLP2 partials [2][4096*768] bf16

  dim3 tb(32, 8);
  // merged preprocessing: weight transposes + w1 shifts + LayerNorm1
  k_pre<<<dim3(24, 483), tb, 0, stream>>>(wq, wk, wv, wo, wvqc, w2, w1, x, ln1g,
                                          ln1b, wqkvT, woT, wvqcT, w2T, w1s, xn);
  k_b1eff<<<3072, 256, 0, stream>>>(b1, wvqcT, bvqc, b1e);
  // W1effT[j*4+i][e] = sum_m wvqcT[j][m] * w1s[i][e][m]
  k_gemm<3, 64, 64, 64><<<dim3(12, 12, 4), 256, 0, stream>>>(
      wvqcT, w1s, 768, 768, 768, nullptr, nullptr, nullptr, nullptr, nullptr,
      W1eT, nullptr, nullptr, 768);
  // QKV: V written directly as V^T psi-permuted (k_vT fused away)
  k_gemm<0, 128, 64, 64><<<dim3(32, 36), 256, 0, stream>>>(
      xn, wqkvT, 768, 768, 768, bq, bk, bv, nullptr, nullptr, qb, kb, vb, 0);
  // xn dead from here. w1s dead; lpart overlays it.
  k_attn<<<dim3(16, 24, 2), 256, 0, stream>>>(qb, kb, vb, vals, opart1, lpart);
  k_comb<<<1536, 256, 0, stream>>>(vals, opart1, lpart, vals);
  // x2b = bf16(x + vals @ woT + bo)  (MODE 6)
  k_gemm<6, 64, 64, 64><<<dim3(64, 12), 256, 0, stream>>>(
      vals, woT, 768, 768, 768, bo, nullptr, nullptr, nullptr, x, x2b, nullptr,
      nullptr, 768);
  k_lnb<<<4096, 256, 0, stream>>>(x2b, ln2g, ln2b, xn2);
  k_gemm<2, 128, 64, 64><<<dim3(32, 48), 256, 0, stream>>>(
      xn2, W1eT, 768, 768, 768, b1e, nullptr, nullptr, nullptr, nullptr, G,
      nullptr, nullptr, 3072);
  // MLP2 split-K=2: bf16 partials (direct store) then combine with resid+bias
  k_gemm<5, 64, 64, 64><<<dim3(64, 12, 2), 256, 0, stream>>>(
      G, w2T, 3072, 3072, 1536, nullptr, nullptr, nullptr, nullptr, nullptr, mp,
      nullptr, nullptr, 768);
  k_fin<<<3072, 256, 0, stream>>>(x2b, b2, mp, out);
}

// Round 25
// 189.397 us; speedup vs baseline: 1.0208x; 1.0056x over previous
//
#include <hip/hip_runtime.h>
#include <hip/hip_bf16.h>
#include <math.h>

typedef unsigned short ushort_t; // bf16 bits
typedef __attribute__((ext_vector_type(4))) short s16x4;
typedef __attribute__((ext_vector_type(8))) short short8;
typedef __attribute__((ext_vector_type(8))) __bf16 bf16x8;
typedef __attribute__((ext_vector_type(4))) float f32x4;
typedef __attribute__((ext_vector_type(4))) unsigned u32x4;

#define SDIM 2048
#define EDIM 768
#define NTOK 4096

static __device__ __forceinline__ ushort_t f2bf(float f) {
  unsigned u = __builtin_bit_cast(unsigned, f);
  u += 0x7fff + ((u >> 16) & 1);
  return (ushort_t)(u >> 16);
}
static __device__ __forceinline__ float bf2f(ushort_t h) {
  return __builtin_bit_cast(float, (unsigned)h << 16);
}
static __device__ __forceinline__ f32x4 mfma16(short8 a, short8 b, f32x4 c) {
  return __builtin_amdgcn_mfma_f32_16x16x32_bf16(
      __builtin_bit_cast(bf16x8, a), __builtin_bit_cast(bf16x8, b), c, 0, 0, 0);
}
static __device__ __forceinline__ void gload_lds16(const void* g, void* l) {
  __builtin_amdgcn_global_load_lds(
      (const __attribute__((address_space(1))) void*)g,
      (__attribute__((address_space(3))) void*)l, 16, 0, 0);
}
static __device__ __forceinline__ unsigned cvtpk(float lo, float hi) {
  unsigned r;
  asm("v_cvt_pk_bf16_f32 %0, %1, %2" : "=v"(r) : "v"(lo), "v"(hi));
  return r;
}
static __device__ __forceinline__ float exp2fast(float x) {
  float r;
  asm("v_exp_f32 %0, %1" : "=v"(r) : "v"(x));
  return r;
}

// ---------- merged preprocessing ----------
// grid (24, 321), block (32,8):
//   y in [0,30): five 768x768 transposes, 128x32 strips (y/6 selects weight)
//   y in [30,54): w2 [3072][768] -> w2T, 128x32 strips
//   y in [54,150): w1 shifted copies w1s[i][e][m] = w1[e][i+m]
//   y in [150,321): LayerNorm1 rows (row = (y-150)*24 + blockIdx.x)
__global__ void k_pre(const float* __restrict__ wq, const float* __restrict__ wk,
                      const float* __restrict__ wv, const float* __restrict__ wo,
                      const float* __restrict__ wvqc, const float* __restrict__ w2,
                      const float* __restrict__ w1, const float* __restrict__ x,
                      const float* __restrict__ ln1g, const float* __restrict__ ln1b,
                      ushort_t* __restrict__ oqkv, ushort_t* __restrict__ owo,
                      ushort_t* __restrict__ ovqc, ushort_t* __restrict__ w2T,
                      ushort_t* __restrict__ w1s, ushort_t* __restrict__ xn) {
  const int y = blockIdx.y;
  const int tx = threadIdx.x, ty = threadIdx.y;
  __shared__ float tile[128][33];
  __shared__ float red[8];
  if (y < 54) {
    const float* in;
    ushort_t* out;
    int R, r0;
    const int c0 = blockIdx.x * 32;
    if (y < 30) {
      const int z = y / 6, ry = y - z * 6;
      in = z == 0 ? wq : z == 1 ? wk : z == 2 ? wv : z == 3 ? wo : wvqc;
      out = z < 3 ? oqkv + (size_t)z * 768 * 768 : (z == 3 ? owo : ovqc);
      R = 768;
      r0 = ry * 128;
    } else {
      in = w2;
      out = w2T;
      R = 3072;
      r0 = (y - 30) * 128;
    }
#pragma unroll
    for (int i = 0; i < 128; i += 8)
      tile[i + ty][tx] = in[(size_t)(r0 + i + ty) * 768 + c0 + tx];
    __syncthreads();
#pragma unroll
    for (int i = 0; i < 32; i += 8) {
      s16x4 v;
#pragma unroll
      for (int j = 0; j < 4; j++) v[j] = (short)f2bf(tile[tx * 4 + j][i + ty]);
      *(s16x4*)(out + (size_t)(c0 + i + ty) * R + r0 + tx * 4) = v;
    }
  } else if (y < 150) {
    const int idx = ((y - 54) * 24 + blockIdx.x) * 256 + ty * 32 + tx;
    const int e = idx / 768, m = idx - (idx / 768) * 768;
#pragma unroll
    for (int i = 0; i < 4; i++)
      w1s[((size_t)i * 768 + e) * 768 + m] = f2bf(w1[(size_t)e * 3072 + i + m]);
  } else {
    const int row = (y - 150) * 24 + blockIdx.x;
    if (row >= NTOK) return;
    const int t = ty * 32 + tx;
    const float* xr = x + (size_t)row * EDIM;
    float v0 = xr[t], v1 = xr[t + 256], v2 = xr[t + 512];
    float s = v0 + v1 + v2;
    float s2 = v0 * v0 + v1 * v1 + v2 * v2;
#pragma unroll
    for (int m = 32; m; m >>= 1) {
      s += __shfl_xor(s, m);
      s2 += __shfl_xor(s2, m);
    }
    const int wid = t >> 6, lane = t & 63;
    if (lane == 0) { red[wid] = s; red[4 + wid] = s2; }
    __syncthreads();
    s = red[0] + red[1] + red[2] + red[3];
    s2 = red[4] + red[5] + red[6] + red[7];
    float mean = s * (1.f / EDIM);
    float var = s2 * (1.f / EDIM) - mean * mean;
    float rstd = rsqrtf(var + 1e-5f);
    ushort_t* orow = xn + (size_t)row * EDIM;
    orow[t] = f2bf((v0 - mean) * rstd * ln1g[t] + ln1b[t]);
    orow[t + 256] = f2bf((v1 - mean) * rstd * ln1g[t + 256] + ln1b[t + 256]);
    orow[t + 512] = f2bf((v2 - mean) * rstd * ln1g[t + 512] + ln1b[t + 512]);
  }
}

// ---------- b1eff[n] = sum_m b1[i+m]*wvqc[m][j] + bvqc[j], n=j*4+i ----------
__global__ __launch_bounds__(256) void k_b1eff(const float* __restrict__ b1,
                                               const ushort_t* __restrict__ wvqcT,
                                               const float* __restrict__ bvqc,
                                               float* __restrict__ b1e) {
  const int n = blockIdx.x; // 3072
  const int i = n & 3, j = n >> 2;
  const int t = threadIdx.x;
  float s = 0.f;
  for (int m = t; m < 768; m += 256)
    s += b1[i + m] * bf2f(wvqcT[(size_t)j * 768 + m]);
#pragma unroll
  for (int mm = 32; mm; mm >>= 1) s += __shfl_xor(s, mm);
  __shared__ float red[4];
  if ((t & 63) == 0) red[t >> 6] = s;
  __syncthreads();
  if (t == 0) b1e[n] = red[0] + red[1] + red[2] + red[3] + bvqc[j];
}

// ---------- LayerNorm row kernel: bf16 in -> bf16 out ----------
__global__ __launch_bounds__(256) void k_lnb(const ushort_t* __restrict__ x,
                                             const float* __restrict__ gam,
                                             const float* __restrict__ bet,
                                             ushort_t* __restrict__ out) {
  const int row = blockIdx.x, t = threadIdx.x;
  const ushort_t* xr = x + (size_t)row * EDIM;
  float v0 = bf2f(xr[t]), v1 = bf2f(xr[t + 256]), v2 = bf2f(xr[t + 512]);
  float s = v0 + v1 + v2;
  float s2 = v0 * v0 + v1 * v1 + v2 * v2;
#pragma unroll
  for (int m = 32; m; m >>= 1) { s += __shfl_xor(s, m); s2 += __shfl_xor(s2, m); }
  __shared__ float red[8];
  const int wid = t >> 6, lane = t & 63;
  if (lane == 0) { red[wid] = s; red[4 + wid] = s2; }
  __syncthreads();
  s = red[0] + red[1] + red[2] + red[3];
  s2 = red[4] + red[5] + red[6] + red[7];
  float mean = s * (1.f / EDIM);
  float var = s2 * (1.f / EDIM) - mean * mean;
  float rstd = rsqrtf(var + 1e-5f);
  ushort_t* orow = out + (size_t)row * EDIM;
  orow[t] = f2bf((v0 - mean) * rstd * gam[t] + bet[t]);
  orow[t + 256] = f2bf((v1 - mean) * rstd * gam[t + 256] + bet[t + 256]);
  orow[t + 512] = f2bf((v2 - mean) * rstd * gam[t + 512] + bet[t + 512]);
}

// ---------- GEMM, templated BK, T2 swizzled LDS, 32KB double-buffer ----------
// 0: QKV scatter (+bias; V written transposed+psi-permuted as [bh][d][psi(t)])
// 1: f32 out = resid + acc + bias     2: gelu(acc+bias) -> bf16
// 3: W1effT store row*4+z             5: split-K partial -> bf16 buffer z
// 6: bf16 out = resid(f32) + acc + bias
template <int MODE, int BM, int BN, int BK>
__global__ __launch_bounds__(256) void k_gemm(
    const ushort_t* __restrict__ A, const ushort_t* __restrict__ Bt, int lda,
    int ldb, int kc, const float* __restrict__ b0, const float* __restrict__ b1p,
    const float* __restrict__ b2p, float* __restrict__ outF,
    const float* __restrict__ resid, ushort_t* __restrict__ o0,
    ushort_t* __restrict__ o1, ushort_t* __restrict__ o2, int ldc) {
  constexpr int MT = BM / 32, NT = BN / 32; // frags per wave (2x2 wave grid)
  constexpr int KCH = BK / 8;               // 16B chunks per row
  constexpr int NPA = BM * BK / 2048;       // staging passes (4KB each)
  constexpr int NPB = BN * BK / 2048;
  constexpr int ROWSP = 2048 / BK;          // rows per staging pass
  constexpr int KK = BK / 32;
  __shared__ ushort_t As[2][BM * BK];
  __shared__ ushort_t Bs[2][BN * BK];
  const int t = threadIdx.x;
  const int m0 = blockIdx.x * BM, n0 = blockIdx.y * BN;
  if (MODE == 3) Bt += (size_t)blockIdx.z * 768 * 768;
  const int koff = (MODE == 5) ? blockIdx.z * kc : 0;
  const int srow = t / KCH, sch = t % KCH;
  const int xs = (BK == 64) ? (srow & 7) : ((srow >> 1) & 3);
  const int gseg = (sch ^ xs) * 8; // inverse-swizzled global chunk
  const ushort_t* ga = A + (size_t)(m0 + srow) * lda + koff + gseg;
  const ushort_t* gb = Bt + (size_t)(n0 + srow) * ldb + koff + gseg;
  const int ldst = t * 8;
  const int lane = t & 63, wid = t >> 6;
  const int g = lane >> 4, c = lane & 15;
  const int wm = (wid >> 1) * (BM / 2), wn = (wid & 1) * (BN / 2);
  const int xc = (BK == 64) ? (c & 7) : ((c >> 1) & 3);
  f32x4 acc[MT][NT] = {};

#define STAGE(BUF, K0)                                                           \
  {                                                                              \
    _Pragma("unroll") for (int p = 0; p < NPA; p++)                              \
        gload_lds16(ga + (K0) + (size_t)(p * ROWSP) * lda,                       \
                    As[BUF] + p * 2048 + ldst);                                  \
    _Pragma("unroll") for (int p = 0; p < NPB; p++)                              \
        gload_lds16(gb + (K0) + (size_t)(p * ROWSP) * ldb,                       \
                    Bs[BUF] + p * 2048 + ldst);                                  \
  }

  STAGE(0, 0);
  __syncthreads();
  int cur = 0;
  for (int k0 = 0; k0 < kc; k0 += BK) {
    if (k0 + BK < kc) STAGE(cur ^ 1, k0 + BK);
    short8 af[KK][MT], bfr[KK][NT];
#pragma unroll
    for (int kk = 0; kk < KK; kk++) {
#pragma unroll
      for (int mt = 0; mt < MT; mt++)
        af[kk][mt] = *(const short8*)(As[cur] + (wm + mt * 16 + c) * BK +
                                      (((g + kk * 4) ^ xc) * 8));
#pragma unroll
      for (int nt = 0; nt < NT; nt++)
        bfr[kk][nt] = *(const short8*)(Bs[cur] + (wn + nt * 16 + c) * BK +
                                       (((g + kk * 4) ^ xc) * 8));
    }
    __builtin_amdgcn_s_setprio(1);
#pragma unroll
    for (int kk = 0; kk < KK; kk++)
#pragma unroll
      for (int mt = 0; mt < MT; mt++)
#pragma unroll
        for (int nt = 0; nt < NT; nt++)
          acc[mt][nt] = mfma16(af[kk][mt], bfr[kk][nt], acc[mt][nt]);
    __builtin_amdgcn_s_setprio(0);
    __syncthreads();
    cur ^= 1;
  }
#undef STAGE

  if constexpr (MODE == 0) {
#pragma unroll
    for (int mt = 0; mt < MT; mt++) {
#pragma unroll
      for (int nt = 0; nt < NT; nt++) {
        const int row0 = m0 + wm + mt * 16 + g * 4;
        const int col = n0 + wn + nt * 16 + c;
        const int which = col / 768; // block-uniform (BN=64 | 768)
        const int nn = col - which * 768;
        const int h = nn >> 6, d = nn & 63;
        const int bb = row0 >> 11, s0 = row0 & 2047;
        if (which == 2) {
          // V: transposed + psi-permuted store, 4 consecutive tokens -> 8B
          const int tl = s0 & 63;
          const int tp = (s0 & ~63) + 32 * (tl >> 5) + 8 * ((tl >> 2) & 3) +
                         4 * ((tl >> 4) & 1);
          s16x4 pv;
#pragma unroll
          for (int r = 0; r < 4; r++)
            pv[r] = (short)f2bf(acc[mt][nt][r] + b2p[nn]);
          *(s16x4*)(o2 + ((size_t)(bb * 12 + h) * 64 + d) * SDIM + tp) = pv;
        } else {
          const float* bp = which == 0 ? b0 : b1p;
          ushort_t* dp = which == 0 ? o0 : o1;
#pragma unroll
          for (int r = 0; r < 4; r++)
            dp[((size_t)(bb * 12 + h) * SDIM + s0 + r) * 64 + d] =
                f2bf(acc[mt][nt][r] + bp[nn]);
        }
      }
    }
    return;
  }

#pragma unroll
  for (int mt = 0; mt < MT; mt++) {
#pragma unroll
    for (int nt = 0; nt < NT; nt++) {
#pragma unroll
      for (int r = 0; r < 4; r++) {
        int row = m0 + wm + mt * 16 + g * 4 + r;
        int col = n0 + wn + nt * 16 + c;
        float val = acc[mt][nt][r];
        if constexpr (MODE == 1) {
          size_t o = (size_t)row * ldc + col;
          outF[o] = resid[o] + val + b0[col];
        } else if constexpr (MODE == 2) {
          float xg = val + b0[col];
          float z2 = xg * (1.5957691216f + 0.0713548162f * xg * xg);
          float ge = xg / (1.f + __expf(-z2));
          o0[(size_t)row * ldc + col] = f2bf(ge);
        } else if constexpr (MODE == 5) {
          o0[(size_t)blockIdx.z * (NTOK * 768) + (size_t)row * ldc + col] =
              f2bf(val);
        } else if constexpr (MODE == 6) {
          size_t o = (size_t)row * ldc + col;
          o0[o] = f2bf(resid[o] + val + b0[col]);
        } else {
          o0[((size_t)row * 4 + blockIdx.z) * ldc + col] = f2bf(val);
        }
      }
    }
  }
}

// ---------- flash attention v9: 32 q-rows/wave, split-KV x2, inline q-norm ----
__global__ __launch_bounds__(256) void k_attn(
    const ushort_t* __restrict__ q, const ushort_t* __restrict__ k,
    const ushort_t* __restrict__ vt, ushort_t* __restrict__ o0p,
    ushort_t* __restrict__ o1p, float* __restrict__ lpart) {
  const int tid = threadIdx.x;
  const int wid = tid >> 6, lane = tid & 63;
  const int g = lane >> 4, c = lane & 15;
  const int bh = blockIdx.y;
  const int z = blockIdx.z;
  const int tbase = z * (SDIM / 2);
  const int q0 = blockIdx.x * 128 + wid * 32;
  const int bb = bh / 12, h = bh - bb * 12;
  const ushort_t* qb = q + (size_t)bh * SDIM * 64;
  const ushort_t* kb = k + (size_t)bh * SDIM * 64;
  const ushort_t* vb = vt + (size_t)bh * 64 * SDIM;

  __shared__ ushort_t Ks[2][64 * 64]; // linear, swizzled content
  __shared__ ushort_t Vs[2][64 * 64];

  short8 bq[2][2];
#pragma unroll
  for (int qg = 0; qg < 2; qg++) {
    short8 a0 = *(const short8*)(qb + (size_t)(q0 + qg * 16 + c) * 64 + g * 8);
    short8 a1 =
        *(const short8*)(qb + (size_t)(q0 + qg * 16 + c) * 64 + 32 + g * 8);
    float s = 0.f;
#pragma unroll
    for (int j = 0; j < 8; j++) {
      float f0 = bf2f((ushort_t)a0[j]), f1 = bf2f((ushort_t)a1[j]);
      s += f0 * f0 + f1 * f1;
    }
    s += __shfl_xor(s, 16);
    s += __shfl_xor(s, 32);
    const float scq = rsqrtf(64.f * fmaxf(s, 1e-5f)) * 1.44269504089f;
#pragma unroll
    for (int j = 0; j < 8; j++) {
      bq[qg][0][j] = (short)f2bf(bf2f((ushort_t)a0[j]) * scq);
      bq[qg][1][j] = (short)f2bf(bf2f((ushort_t)a1[j]) * scq);
    }
  }
  const short8 ones = {0x3F80, 0x3F80, 0x3F80, 0x3F80,
                       0x3F80, 0x3F80, 0x3F80, 0x3F80}; // bf16 1.0 x8

  const int srow = tid >> 3, sj = tid & 7;

#define STAGE(BUF, T0)                                                          \
  {                                                                             \
    _Pragma("unroll") for (int n = 0; n < 2; n++) {                             \
      const int row = n * 32 + srow;                                            \
      const int scol = (sj ^ (row & 7)) * 8;                                    \
      gload_lds16(kb + (size_t)((T0) + row) * 64 + scol,                        \
                  Ks[BUF] + n * 2048 + tid * 8);                                \
      gload_lds16(vb + (size_t)row * SDIM + (T0) + scol,                        \
                  Vs[BUF] + n * 2048 + tid * 8);                                \
    }                                                                           \
  }

  f32x4 accO[2][4] = {};
  f32x4 accL[2] = {};
  const int sw = (c & 7) << 4;

  STAGE(0, tbase);
  __syncthreads();
  int cur = 0;
  for (int tt = 0; tt < SDIM / 128; tt++) {
    const int t0 = tbase + tt * 64;
    if (tt + 1 < SDIM / 128) STAGE(cur ^ 1, t0 + 64);
    const char* Kc = (const char*)Ks[cur];
    const char* Vc = (const char*)Vs[cur];
    f32x4 s0[4] = {}, s1[4] = {};
    __builtin_amdgcn_s_setprio(1);
#pragma unroll
    for (int i = 0; i < 4; i++) {
      const int rb = (i * 16 + c) * 128;
      short8 ka0 = *(const short8*)(Kc + rb + ((g * 16) ^ sw));
      short8 ka1 = *(const short8*)(Kc + rb + ((64 + g * 16) ^ sw));
      s0[i] = mfma16(ka0, bq[0][0], s0[i]);
      s1[i] = mfma16(ka0, bq[1][0], s1[i]);
      s0[i] = mfma16(ka1, bq[0][1], s0[i]);
      s1[i] = mfma16(ka1, bq[1][1], s1[i]);
    }
    __builtin_amdgcn_s_setprio(0);
    u32x4 w00 = {cvtpk(exp2fast(s0[0][0]), exp2fast(s0[0][1])),
                 cvtpk(exp2fast(s0[0][2]), exp2fast(s0[0][3])),
                 cvtpk(exp2fast(s0[1][0]), exp2fast(s0[1][1])),
                 cvtpk(exp2fast(s0[1][2]), exp2fast(s0[1][3]))};
    u32x4 w10 = {cvtpk(exp2fast(s1[0][0]), exp2fast(s1[0][1])),
                 cvtpk(exp2fast(s1[0][2]), exp2fast(s1[0][3])),
                 cvtpk(exp2fast(s1[1][0]), exp2fast(s1[1][1])),
                 cvtpk(exp2fast(s1[1][2]), exp2fast(s1[1][3]))};
    u32x4 w01 = {cvtpk(exp2fast(s0[2][0]), exp2fast(s0[2][1])),
                 cvtpk(exp2fast(s0[2][2]), exp2fast(s0[2][3])),
                 cvtpk(exp2fast(s0[3][0]), exp2fast(s0[3][1])),
                 cvtpk(exp2fast(s0[3][2]), exp2fast(s0[3][3]))};
    u32x4 w11 = {cvtpk(exp2fast(s1[2][0]), exp2fast(s1[2][1])),
                 cvtpk(exp2fast(s1[2][2]), exp2fast(s1[2][3])),
                 cvtpk(exp2fast(s1[3][0]), exp2fast(s1[3][1])),
                 cvtpk(exp2fast(s1[3][2]), exp2fast(s1[3][3]))};
    short8 pa00 = __builtin_bit_cast(short8, w00);
    short8 pa01 = __builtin_bit_cast(short8, w01);
    short8 pa10 = __builtin_bit_cast(short8, w10);
    short8 pa11 = __builtin_bit_cast(short8, w11);
    __builtin_amdgcn_s_setprio(1);
    accL[0] = mfma16(pa00, ones, accL[0]);
    accL[1] = mfma16(pa10, ones, accL[1]);
    accL[0] = mfma16(pa01, ones, accL[0]);
    accL[1] = mfma16(pa11, ones, accL[1]);
#pragma unroll
    for (int dt = 0; dt < 4; dt++) {
      const int vbse = (dt * 16 + c) * 128;
      short8 v0 = *(const short8*)(Vc + vbse + ((g * 16) ^ sw));
      short8 v1 = *(const short8*)(Vc + vbse + ((64 + g * 16) ^ sw));
      accO[0][dt] = mfma16(pa00, v0, accO[0][dt]);
      accO[1][dt] = mfma16(pa10, v0, accO[1][dt]);
      accO[0][dt] = mfma16(pa01, v1, accO[0][dt]);
      accO[1][dt] = mfma16(pa11, v1, accO[1][dt]);
    }
    __builtin_amdgcn_s_setprio(0);
    __syncthreads();
    cur ^= 1;
  }
#undef STAGE

  ushort_t* op = z ? o1p : o0p;
#pragma unroll
  for (int qg = 0; qg < 2; qg++) {
    if (c == 0) {
#pragma unroll
      for (int r = 0; r < 4; r++)
        lpart[((size_t)z * 24 + bh) * SDIM + q0 + qg * 16 + 4 * g + r] =
            accL[qg][r];
    }
#pragma unroll
    for (int dt = 0; dt < 4; dt++)
#pragma unroll
      for (int r = 0; r < 4; r++) {
        int s = q0 + qg * 16 + 4 * g + r;
        op[((size_t)(bb * SDIM + s)) * EDIM + h * 64 + dt * 16 + c] =
            f2bf(accO[qg][dt][r]);
      }
  }
}

// ---------- combine split-KV partials: vals = (O0+O1)/(l0+l1) ----------
__global__ __launch_bounds__(256) void k_comb(const ushort_t* __restrict__ o0p,
                                              const ushort_t* __restrict__ o1p,
                                              const float* __restrict__ lpart,
                                              ushort_t* __restrict__ vals) {
  const int gid = blockIdx.x * 256 + threadIdx.x; // < 4096*96
  const int tok = gid / 96, ch = gid - tok * 96;
  const int h = ch >> 3;
  const int bb = tok >> 11, s = tok & 2047;
  const size_t lrow = (size_t)(bb * 12 + h) * SDIM + s;
  const float inv = 1.f / (lpart[lrow] + lpart[(size_t)24 * SDIM + lrow]);
  short8 a = *(const short8*)(o0p + (size_t)gid * 8);
  short8 b = *(const short8*)(o1p + (size_t)gid * 8);
  short8 o;
#pragma unroll
  for (int j = 0; j < 8; j++)
    o[j] = (short)f2bf((bf2f((ushort_t)a[j]) + bf2f((ushort_t)b[j])) * inv);
  *(short8*)(vals + (size_t)gid * 8) = o;
}

// ---------- final: out = x2(bf16) + b2 + p0 + p1 (MLP2 split-K combine) ------
__global__ __launch_bounds__(256) void k_fin(const ushort_t* __restrict__ x2b,
                                             const float* __restrict__ b2,
                                             const ushort_t* __restrict__ p,
                                             float* __restrict__ out) {
  const int i = blockIdx.x * 256 + threadIdx.x; // < 786432 (f32x4 groups)
  s16x4 rx = ((const s16x4*)x2b)[i];
  f32x4 b = ((const f32x4*)b2)[i % 192];
  s16x4 a0 = ((const s16x4*)p)[i];
  s16x4 a1 = ((const s16x4*)(p + (size_t)NTOK * 768))[i];
  f32x4 o;
#pragma unroll
  for (int j = 0; j < 4; j++)
    o[j] = bf2f((ushort_t)rx[j]) + b[j] + bf2f((ushort_t)a0[j]) +
           bf2f((ushort_t)a1[j]);
  ((f32x4*)out)[i] = o;
}

extern "C" void kernel_launch(void* const* d_in, const int* in_sizes, int n_in,
                              void* d_out, int out_size, void* d_ws, size_t ws_size,
                              hipStream_t stream) {
  const float* x = (const float*)d_in[0];
  const float* ln1g = (const float*)d_in[1];
  const float* ln1b = (const float*)d_in[2];
  const float* wq = (const float*)d_in[3];
  const float* bq = (const float*)d_in[4];
  const float* wk = (const float*)d_in[5];
  const float* bk = (const float*)d_in[6];
  const float* wv = (const float*)d_in[7];
  const float* bv = (const float*)d_in[8];
  const float* wo = (const float*)d_in[9];
  const float* bo = (const float*)d_in[10];
  const float* ln2g = (const float*)d_in[11];
  const float* ln2b = (const float*)d_in[12];
  const float* w1 = (const float*)d_in[13];
  const float* b1 = (const float*)d_in[14];
  const float* wvqc = (const float*)d_in[15];
  const float* bvqc = (const float*)d_in[16];
  const float* w2 = (const float*)d_in[17];
  const float* b2 = (const float*)d_in[18];
  float* out = (float*)d_out;

  char* w = (char*)d_ws;
  ushort_t* xn = (ushort_t*)(w + 0);           // 6291456 (dead after QKV gemm)
  ushort_t* xn2 = (ushort_t*)(w + 6291456);    // 6291456; Opart1 before LN2
  ushort_t* opart1 = (ushort_t*)(w + 6291456);
  ushort_t* x2b = (ushort_t*)(w + 12582912);   // bf16 residual, 6291456
  ushort_t* qb = (ushort_t*)(w + 25165824);    // 6291456
  ushort_t* kb = (ushort_t*)(w + 31457280);    // 6291456
  ushort_t* vb = (ushort_t*)(w + 37748736);    // 6291456 (V^T psi layout)
  ushort_t* vals = (ushort_t*)(w + 44040192);  // 6291456; Opart0 (in-place comb)
  ushort_t* G = (ushort_t*)(w + 25165824);     // overlays q..vals
  ushort_t* wqkvT = (ushort_t*)(w + 50528256); // 3538944
  ushort_t* woT = (ushort_t*)(w + 54067200);   // 1179648
  ushort_t* wvqcT = (ushort_t*)(w + 55246848); // 1179648
  ushort_t* w1s = (ushort_t*)(w + 56426496);   // 4718592; lpart after W1eff gemm
  float* lpart = (float*)(w + 56426496);       // 393216 (dead w1s)
  ushort_t* W1eT = (ushort_t*)(w + 61145088);  // 4718592
  float* b1e = (float*)(w + 65863680);         // 12288
  ushort_t* w2T = (ushort_t*)(w + 65875968);   // 4718592 -> end 70594560
  ushort_t* mp = (ushort_t*)(w + 0); // MLP2 partials [2][4096*768] bf16

  dim3 tb(32, 8);
  // merged preprocessing: weight transposes + w1 shifts + LayerNorm1
  k_pre<<<dim3(24, 321), tb, 0, stream>>>(wq, wk, wv, wo, wvqc, w2, w1, x, ln1g,
                                          ln1b, wqkvT, woT, wvqcT, w2T, w1s, xn);
  k_b1eff<<<3072, 256, 0, stream>>>(b1, wvqcT, bvqc, b1e);
  // W1effT[j*4+i][e] = sum_m wvqcT[j][m] * w1s[i][e][m]
  k_gemm<3, 64, 64, 64><<<dim3(12, 12, 4), 256, 0, stream>>>(
      wvqcT, w1s, 768, 768, 768, nullptr, nullptr, nullptr, nullptr, nullptr,
      W1eT, nullptr, nullptr, 768);
  // QKV: V written directly as V^T psi-permuted (k_vT fused away)
  k_gemm<0, 128, 64, 64><<<dim3(32, 36), 256, 0, stream>>>(
      xn, wqkvT, 768, 768, 768, bq, bk, bv, nullptr, nullptr, qb, kb, vb, 0);
  // xn dead from here. w1s dead; lpart overlays it.
  k_attn<<<dim3(16, 24, 2), 256, 0, stream>>>(qb, kb, vb, vals, opart1, lpart);
  k_comb<<<1536, 256, 0, stream>>>(vals, opart1, lpart, vals);
  // x2b = bf16(x + vals @ woT + bo)  (MODE 6)
  k_gemm<6, 64, 64, 64><<<dim3(64, 12), 256, 0, stream>>>(
      vals, woT, 768, 768, 768, bo, nullptr, nullptr, nullptr, x, x2b, nullptr,
      nullptr, 768);
  k_lnb<<<4096, 256, 0, stream>>>(x2b, ln2g, ln2b, xn2);
  k_gemm<2, 128, 64, 64><<<dim3(32, 48), 256, 0, stream>>>(
      xn2, W1eT, 768, 768, 768, b1e, nullptr, nullptr, nullptr, nullptr, G,
      nullptr, nullptr, 3072);
  // MLP2 split-K=2: bf16 partials (direct store) then combine with resid+bias
  k_gemm<5, 64, 64, 64><<<dim3(64, 12, 2), 256, 0, stream>>>(
      G, w2T, 3072, 3072, 1536, nullptr, nullptr, nullptr, nullptr, nullptr, mp,
      nullptr, nullptr, 768);
  k_fin<<<3072, 256, 0, stream>>>(x2b, b2, mp, out);
}

// Round 26
// 186.791 us; speedup vs baseline: 1.0351x; 1.0139x over previous
//
#include <hip/hip_runtime.h>
#include <hip/hip_bf16.h>
#include <math.h>

typedef unsigned short ushort_t; // bf16 bits
typedef __attribute__((ext_vector_type(4))) short s16x4;
typedef __attribute__((ext_vector_type(8))) short short8;
typedef __attribute__((ext_vector_type(8))) __bf16 bf16x8;
typedef __attribute__((ext_vector_type(4))) float f32x4;
typedef __attribute__((ext_vector_type(4))) unsigned u32x4;

#define SDIM 2048
#define EDIM 768
#define NTOK 4096

static __device__ __forceinline__ ushort_t f2bf(float f) {
  unsigned u = __builtin_bit_cast(unsigned, f);
  u += 0x7fff + ((u >> 16) & 1);
  return (ushort_t)(u >> 16);
}
static __device__ __forceinline__ float bf2f(ushort_t h) {
  return __builtin_bit_cast(float, (unsigned)h << 16);
}
static __device__ __forceinline__ f32x4 mfma16(short8 a, short8 b, f32x4 c) {
  return __builtin_amdgcn_mfma_f32_16x16x32_bf16(
      __builtin_bit_cast(bf16x8, a), __builtin_bit_cast(bf16x8, b), c, 0, 0, 0);
}
static __device__ __forceinline__ void gload_lds16(const void* g, void* l) {
  __builtin_amdgcn_global_load_lds(
      (const __attribute__((address_space(1))) void*)g,
      (__attribute__((address_space(3))) void*)l, 16, 0, 0);
}
static __device__ __forceinline__ unsigned cvtpk(float lo, float hi) {
  unsigned r;
  asm("v_cvt_pk_bf16_f32 %0, %1, %2" : "=v"(r) : "v"(lo), "v"(hi));
  return r;
}
static __device__ __forceinline__ float exp2fast(float x) {
  float r;
  asm("v_exp_f32 %0, %1" : "=v"(r) : "v"(x));
  return r;
}

// ---------- merged preprocessing ----------
// grid (24, 321), block (32,8):
//   y in [0,30): five 768x768 transposes, 128x32 strips (y/6 selects weight)
//   y in [30,54): w2 [3072][768] -> w2T, 128x32 strips
//   y in [54,150): w1 shifted copies w1s[i][e][m] = w1[e][i+m]
//   y in [150,321): LayerNorm1 rows (row = (y-150)*24 + blockIdx.x)
__global__ void k_pre(const float* __restrict__ wq, const float* __restrict__ wk,
                      const float* __restrict__ wv, const float* __restrict__ wo,
                      const float* __restrict__ wvqc, const float* __restrict__ w2,
                      const float* __restrict__ w1, const float* __restrict__ x,
                      const float* __restrict__ ln1g, const float* __restrict__ ln1b,
                      ushort_t* __restrict__ oqkv, ushort_t* __restrict__ owo,
                      ushort_t* __restrict__ ovqc, ushort_t* __restrict__ w2T,
                      ushort_t* __restrict__ w1s, ushort_t* __restrict__ xn) {
  const int y = blockIdx.y;
  const int tx = threadIdx.x, ty = threadIdx.y;
  __shared__ float tile[128][33];
  __shared__ float red[8];
  if (y < 54) {
    const float* in;
    ushort_t* out;
    int R, r0;
    const int c0 = blockIdx.x * 32;
    if (y < 30) {
      const int z = y / 6, ry = y - z * 6;
      in = z == 0 ? wq : z == 1 ? wk : z == 2 ? wv : z == 3 ? wo : wvqc;
      out = z < 3 ? oqkv + (size_t)z * 768 * 768 : (z == 3 ? owo : ovqc);
      R = 768;
      r0 = ry * 128;
    } else {
      in = w2;
      out = w2T;
      R = 3072;
      r0 = (y - 30) * 128;
    }
#pragma unroll
    for (int i = 0; i < 128; i += 8)
      tile[i + ty][tx] = in[(size_t)(r0 + i + ty) * 768 + c0 + tx];
    __syncthreads();
#pragma unroll
    for (int i = 0; i < 32; i += 8) {
      s16x4 v;
#pragma unroll
      for (int j = 0; j < 4; j++) v[j] = (short)f2bf(tile[tx * 4 + j][i + ty]);
      *(s16x4*)(out + (size_t)(c0 + i + ty) * R + r0 + tx * 4) = v;
    }
  } else if (y < 150) {
    const int idx = ((y - 54) * 24 + blockIdx.x) * 256 + ty * 32 + tx;
    const int e = idx / 768, m = idx - (idx / 768) * 768;
#pragma unroll
    for (int i = 0; i < 4; i++)
      w1s[((size_t)i * 768 + e) * 768 + m] = f2bf(w1[(size_t)e * 3072 + i + m]);
  } else {
    const int row = (y - 150) * 24 + blockIdx.x;
    if (row >= NTOK) return;
    const int t = ty * 32 + tx;
    const float* xr = x + (size_t)row * EDIM;
    float v0 = xr[t], v1 = xr[t + 256], v2 = xr[t + 512];
    float s = v0 + v1 + v2;
    float s2 = v0 * v0 + v1 * v1 + v2 * v2;
#pragma unroll
    for (int m = 32; m; m >>= 1) {
      s += __shfl_xor(s, m);
      s2 += __shfl_xor(s2, m);
    }
    const int wid = t >> 6, lane = t & 63;
    if (lane == 0) { red[wid] = s; red[4 + wid] = s2; }
    __syncthreads();
    s = red[0] + red[1] + red[2] + red[3];
    s2 = red[4] + red[5] + red[6] + red[7];
    float mean = s * (1.f / EDIM);
    float var = s2 * (1.f / EDIM) - mean * mean;
    float rstd = rsqrtf(var + 1e-5f);
    ushort_t* orow = xn + (size_t)row * EDIM;
    orow[t] = f2bf((v0 - mean) * rstd * ln1g[t] + ln1b[t]);
    orow[t + 256] = f2bf((v1 - mean) * rstd * ln1g[t + 256] + ln1b[t + 256]);
    orow[t + 512] = f2bf((v2 - mean) * rstd * ln1g[t + 512] + ln1b[t + 512]);
  }
}

// ---------- LayerNorm2 (bf16 in/out) + fused b1eff reduction ----------
// grid 7168: blocks [0,4096) do LN rows; blocks [4096,7168) compute
// b1eff[n] = sum_m b1[i+m]*wvqcT[j][m] + bvqc[j]  (n = blockIdx.x-4096)
__global__ __launch_bounds__(256) void k_lnb(const ushort_t* __restrict__ x,
                                             const float* __restrict__ gam,
                                             const float* __restrict__ bet,
                                             ushort_t* __restrict__ out,
                                             const float* __restrict__ b1,
                                             const ushort_t* __restrict__ wvqcT,
                                             const float* __restrict__ bvqc,
                                             float* __restrict__ b1e) {
  const int t = threadIdx.x;
  __shared__ float red[8];
  if (blockIdx.x < NTOK) {
    const int row = blockIdx.x;
    const ushort_t* xr = x + (size_t)row * EDIM;
    float v0 = bf2f(xr[t]), v1 = bf2f(xr[t + 256]), v2 = bf2f(xr[t + 512]);
    float s = v0 + v1 + v2;
    float s2 = v0 * v0 + v1 * v1 + v2 * v2;
#pragma unroll
    for (int m = 32; m; m >>= 1) {
      s += __shfl_xor(s, m);
      s2 += __shfl_xor(s2, m);
    }
    const int wid = t >> 6, lane = t & 63;
    if (lane == 0) { red[wid] = s; red[4 + wid] = s2; }
    __syncthreads();
    s = red[0] + red[1] + red[2] + red[3];
    s2 = red[4] + red[5] + red[6] + red[7];
    float mean = s * (1.f / EDIM);
    float var = s2 * (1.f / EDIM) - mean * mean;
    float rstd = rsqrtf(var + 1e-5f);
    ushort_t* orow = out + (size_t)row * EDIM;
    orow[t] = f2bf((v0 - mean) * rstd * gam[t] + bet[t]);
    orow[t + 256] = f2bf((v1 - mean) * rstd * gam[t + 256] + bet[t + 256]);
    orow[t + 512] = f2bf((v2 - mean) * rstd * gam[t + 512] + bet[t + 512]);
  } else {
    const int n = blockIdx.x - NTOK; // < 3072
    const int i = n & 3, j = n >> 2;
    float s = 0.f;
    for (int m = t; m < 768; m += 256)
      s += b1[i + m] * bf2f(wvqcT[(size_t)j * 768 + m]);
#pragma unroll
    for (int mm = 32; mm; mm >>= 1) s += __shfl_xor(s, mm);
    const int wid = t >> 6, lane = t & 63;
    if (lane == 0) red[wid] = s;
    __syncthreads();
    if (t == 0) b1e[n] = red[0] + red[1] + red[2] + red[3] + bvqc[j];
  }
}

// ---------- GEMM, templated BK, T2 swizzled LDS, 32KB double-buffer ----------
// 0: QKV scatter (+bias; V written transposed+psi-permuted as [bh][d][psi(t)])
// 1: f32 out = resid + acc + bias     2: gelu(acc+bias) -> bf16
// 3: W1effT store row*4+z             5: split-K partial -> bf16 buffer z
// 6: bf16 out = resid(f32) + acc + bias
template <int MODE, int BM, int BN, int BK>
__global__ __launch_bounds__(256) void k_gemm(
    const ushort_t* __restrict__ A, const ushort_t* __restrict__ Bt, int lda,
    int ldb, int kc, const float* __restrict__ b0, const float* __restrict__ b1p,
    const float* __restrict__ b2p, float* __restrict__ outF,
    const float* __restrict__ resid, ushort_t* __restrict__ o0,
    ushort_t* __restrict__ o1, ushort_t* __restrict__ o2, int ldc) {
  constexpr int MT = BM / 32, NT = BN / 32; // frags per wave (2x2 wave grid)
  constexpr int KCH = BK / 8;               // 16B chunks per row
  constexpr int NPA = BM * BK / 2048;       // staging passes (4KB each)
  constexpr int NPB = BN * BK / 2048;
  constexpr int ROWSP = 2048 / BK;          // rows per staging pass
  constexpr int KK = BK / 32;
  __shared__ ushort_t As[2][BM * BK];
  __shared__ ushort_t Bs[2][BN * BK];
  const int t = threadIdx.x;
  const int m0 = blockIdx.x * BM, n0 = blockIdx.y * BN;
  if (MODE == 3) Bt += (size_t)blockIdx.z * 768 * 768;
  const int koff = (MODE == 5) ? blockIdx.z * kc : 0;
  const int srow = t / KCH, sch = t % KCH;
  const int xs = (BK == 64) ? (srow & 7) : ((srow >> 1) & 3);
  const int gseg = (sch ^ xs) * 8; // inverse-swizzled global chunk
  const ushort_t* ga = A + (size_t)(m0 + srow) * lda + koff + gseg;
  const ushort_t* gb = Bt + (size_t)(n0 + srow) * ldb + koff + gseg;
  const int ldst = t * 8;
  const int lane = t & 63, wid = t >> 6;
  const int g = lane >> 4, c = lane & 15;
  const int wm = (wid >> 1) * (BM / 2), wn = (wid & 1) * (BN / 2);
  const int xc = (BK == 64) ? (c & 7) : ((c >> 1) & 3);
  f32x4 acc[MT][NT] = {};

#define STAGE(BUF, K0)                                                           \
  {                                                                              \
    _Pragma("unroll") for (int p = 0; p < NPA; p++)                              \
        gload_lds16(ga + (K0) + (size_t)(p * ROWSP) * lda,                       \
                    As[BUF] + p * 2048 + ldst);                                  \
    _Pragma("unroll") for (int p = 0; p < NPB; p++)                              \
        gload_lds16(gb + (K0) + (size_t)(p * ROWSP) * ldb,                       \
                    Bs[BUF] + p * 2048 + ldst);                                  \
  }

  STAGE(0, 0);
  __syncthreads();
  int cur = 0;
  for (int k0 = 0; k0 < kc; k0 += BK) {
    if (k0 + BK < kc) STAGE(cur ^ 1, k0 + BK);
    short8 af[KK][MT], bfr[KK][NT];
#pragma unroll
    for (int kk = 0; kk < KK; kk++) {
#pragma unroll
      for (int mt = 0; mt < MT; mt++)
        af[kk][mt] = *(const short8*)(As[cur] + (wm + mt * 16 + c) * BK +
                                      (((g + kk * 4) ^ xc) * 8));
#pragma unroll
      for (int nt = 0; nt < NT; nt++)
        bfr[kk][nt] = *(const short8*)(Bs[cur] + (wn + nt * 16 + c) * BK +
                                       (((g + kk * 4) ^ xc) * 8));
    }
    __builtin_amdgcn_s_setprio(1);
#pragma unroll
    for (int kk = 0; kk < KK; kk++)
#pragma unroll
      for (int mt = 0; mt < MT; mt++)
#pragma unroll
        for (int nt = 0; nt < NT; nt++)
          acc[mt][nt] = mfma16(af[kk][mt], bfr[kk][nt], acc[mt][nt]);
    __builtin_amdgcn_s_setprio(0);
    __syncthreads();
    cur ^= 1;
  }
#undef STAGE

  if constexpr (MODE == 0) {
#pragma unroll
    for (int mt = 0; mt < MT; mt++) {
#pragma unroll
      for (int nt = 0; nt < NT; nt++) {
        const int row0 = m0 + wm + mt * 16 + g * 4;
        const int col = n0 + wn + nt * 16 + c;
        const int which = col / 768; // block-uniform (BN=64 | 768)
        const int nn = col - which * 768;
        const int h = nn >> 6, d = nn & 63;
        const int bb = row0 >> 11, s0 = row0 & 2047;
        if (which == 2) {
          // V: transposed + psi-permuted store, 4 consecutive tokens -> 8B
          const int tl = s0 & 63;
          const int tp = (s0 & ~63) + 32 * (tl >> 5) + 8 * ((tl >> 2) & 3) +
                         4 * ((tl >> 4) & 1);
          s16x4 pv;
#pragma unroll
          for (int r = 0; r < 4; r++)
            pv[r] = (short)f2bf(acc[mt][nt][r] + b2p[nn]);
          *(s16x4*)(o2 + ((size_t)(bb * 12 + h) * 64 + d) * SDIM + tp) = pv;
        } else {
          const float* bp = which == 0 ? b0 : b1p;
          ushort_t* dp = which == 0 ? o0 : o1;
#pragma unroll
          for (int r = 0; r < 4; r++)
            dp[((size_t)(bb * 12 + h) * SDIM + s0 + r) * 64 + d] =
                f2bf(acc[mt][nt][r] + bp[nn]);
        }
      }
    }
    return;
  }

#pragma unroll
  for (int mt = 0; mt < MT; mt++) {
#pragma unroll
    for (int nt = 0; nt < NT; nt++) {
#pragma unroll
      for (int r = 0; r < 4; r++) {
        int row = m0 + wm + mt * 16 + g * 4 + r;
        int col = n0 + wn + nt * 16 + c;
        float val = acc[mt][nt][r];
        if constexpr (MODE == 1) {
          size_t o = (size_t)row * ldc + col;
          outF[o] = resid[o] + val + b0[col];
        } else if constexpr (MODE == 2) {
          float xg = val + b0[col];
          float z2 = xg * (1.5957691216f + 0.0713548162f * xg * xg);
          float ge = xg / (1.f + __expf(-z2));
          o0[(size_t)row * ldc + col] = f2bf(ge);
        } else if constexpr (MODE == 5) {
          o0[(size_t)blockIdx.z * (NTOK * 768) + (size_t)row * ldc + col] =
              f2bf(val);
        } else if constexpr (MODE == 6) {
          size_t o = (size_t)row * ldc + col;
          o0[o] = f2bf(resid[o] + val + b0[col]);
        } else {
          o0[((size_t)row * 4 + blockIdx.z) * ldc + col] = f2bf(val);
        }
      }
    }
  }
}

// ---------- flash attention v9: 32 q-rows/wave, split-KV x2, inline q-norm ----
__global__ __launch_bounds__(256) void k_attn(
    const ushort_t* __restrict__ q, const ushort_t* __restrict__ k,
    const ushort_t* __restrict__ vt, ushort_t* __restrict__ o0p,
    ushort_t* __restrict__ o1p, float* __restrict__ lpart) {
  const int tid = threadIdx.x;
  const int wid = tid >> 6, lane = tid & 63;
  const int g = lane >> 4, c = lane & 15;
  const int bh = blockIdx.y;
  const int z = blockIdx.z;
  const int tbase = z * (SDIM / 2);
  const int q0 = blockIdx.x * 128 + wid * 32;
  const int bb = bh / 12, h = bh - bb * 12;
  const ushort_t* qb = q + (size_t)bh * SDIM * 64;
  const ushort_t* kb = k + (size_t)bh * SDIM * 64;
  const ushort_t* vb = vt + (size_t)bh * 64 * SDIM;

  __shared__ ushort_t Ks[2][64 * 64]; // linear, swizzled content
  __shared__ ushort_t Vs[2][64 * 64];

  short8 bq[2][2];
#pragma unroll
  for (int qg = 0; qg < 2; qg++) {
    short8 a0 = *(const short8*)(qb + (size_t)(q0 + qg * 16 + c) * 64 + g * 8);
    short8 a1 =
        *(const short8*)(qb + (size_t)(q0 + qg * 16 + c) * 64 + 32 + g * 8);
    float s = 0.f;
#pragma unroll
    for (int j = 0; j < 8; j++) {
      float f0 = bf2f((ushort_t)a0[j]), f1 = bf2f((ushort_t)a1[j]);
      s += f0 * f0 + f1 * f1;
    }
    s += __shfl_xor(s, 16);
    s += __shfl_xor(s, 32);
    const float scq = rsqrtf(64.f * fmaxf(s, 1e-5f)) * 1.44269504089f;
#pragma unroll
    for (int j = 0; j < 8; j++) {
      bq[qg][0][j] = (short)f2bf(bf2f((ushort_t)a0[j]) * scq);
      bq[qg][1][j] = (short)f2bf(bf2f((ushort_t)a1[j]) * scq);
    }
  }
  const short8 ones = {0x3F80, 0x3F80, 0x3F80, 0x3F80,
                       0x3F80, 0x3F80, 0x3F80, 0x3F80}; // bf16 1.0 x8

  const int srow = tid >> 3, sj = tid & 7;

#define STAGE(BUF, T0)                                                          \
  {                                                                             \
    _Pragma("unroll") for (int n = 0; n < 2; n++) {                             \
      const int row = n * 32 + srow;                                            \
      const int scol = (sj ^ (row & 7)) * 8;                                    \
      gload_lds16(kb + (size_t)((T0) + row) * 64 + scol,                        \
                  Ks[BUF] + n * 2048 + tid * 8);                                \
      gload_lds16(vb + (size_t)row * SDIM + (T0) + scol,                        \
                  Vs[BUF] + n * 2048 + tid * 8);                                \
    }                                                                           \
  }

  f32x4 accO[2][4] = {};
  f32x4 accL[2] = {};
  const int sw = (c & 7) << 4;

  STAGE(0, tbase);
  __syncthreads();
  int cur = 0;
  for (int tt = 0; tt < SDIM / 128; tt++) {
    const int t0 = tbase + tt * 64;
    if (tt + 1 < SDIM / 128) STAGE(cur ^ 1, t0 + 64);
    const char* Kc = (const char*)Ks[cur];
    const char* Vc = (const char*)Vs[cur];
    f32x4 s0[4] = {}, s1[4] = {};
    __builtin_amdgcn_s_setprio(1);
#pragma unroll
    for (int i = 0; i < 4; i++) {
      const int rb = (i * 16 + c) * 128;
      short8 ka0 = *(const short8*)(Kc + rb + ((g * 16) ^ sw));
      short8 ka1 = *(const short8*)(Kc + rb + ((64 + g * 16) ^ sw));
      s0[i] = mfma16(ka0, bq[0][0], s0[i]);
      s1[i] = mfma16(ka0, bq[1][0], s1[i]);
      s0[i] = mfma16(ka1, bq[0][1], s0[i]);
      s1[i] = mfma16(ka1, bq[1][1], s1[i]);
    }
    __builtin_amdgcn_s_setprio(0);
    u32x4 w00 = {cvtpk(exp2fast(s0[0][0]), exp2fast(s0[0][1])),
                 cvtpk(exp2fast(s0[0][2]), exp2fast(s0[0][3])),
                 cvtpk(exp2fast(s0[1][0]), exp2fast(s0[1][1])),
                 cvtpk(exp2fast(s0[1][2]), exp2fast(s0[1][3]))};
    u32x4 w10 = {cvtpk(exp2fast(s1[0][0]), exp2fast(s1[0][1])),
                 cvtpk(exp2fast(s1[0][2]), exp2fast(s1[0][3])),
                 cvtpk(exp2fast(s1[1][0]), exp2fast(s1[1][1])),
                 cvtpk(exp2fast(s1[1][2]), exp2fast(s1[1][3]))};
    u32x4 w01 = {cvtpk(exp2fast(s0[2][0]), exp2fast(s0[2][1])),
                 cvtpk(exp2fast(s0[2][2]), exp2fast(s0[2][3])),
                 cvtpk(exp2fast(s0[3][0]), exp2fast(s0[3][1])),
                 cvtpk(exp2fast(s0[3][2]), exp2fast(s0[3][3]))};
    u32x4 w11 = {cvtpk(exp2fast(s1[2][0]), exp2fast(s1[2][1])),
                 cvtpk(exp2fast(s1[2][2]), exp2fast(s1[2][3])),
                 cvtpk(exp2fast(s1[3][0]), exp2fast(s1[3][1])),
                 cvtpk(exp2fast(s1[3][2]), exp2fast(s1[3][3]))};
    short8 pa00 = __builtin_bit_cast(short8, w00);
    short8 pa01 = __builtin_bit_cast(short8, w01);
    short8 pa10 = __builtin_bit_cast(short8, w10);
    short8 pa11 = __builtin_bit_cast(short8, w11);
    __builtin_amdgcn_s_setprio(1);
    accL[0] = mfma16(pa00, ones, accL[0]);
    accL[1] = mfma16(pa10, ones, accL[1]);
    accL[0] = mfma16(pa01, ones, accL[0]);
    accL[1] = mfma16(pa11, ones, accL[1]);
#pragma unroll
    for (int dt = 0; dt < 4; dt++) {
      const int vbse = (dt * 16 + c) * 128;
      short8 v0 = *(const short8*)(Vc + vbse + ((g * 16) ^ sw));
      short8 v1 = *(const short8*)(Vc + vbse + ((64 + g * 16) ^ sw));
      accO[0][dt] = mfma16(pa00, v0, accO[0][dt]);
      accO[1][dt] = mfma16(pa10, v0, accO[1][dt]);
      accO[0][dt] = mfma16(pa01, v1, accO[0][dt]);
      accO[1][dt] = mfma16(pa11, v1, accO[1][dt]);
    }
    __builtin_amdgcn_s_setprio(0);
    __syncthreads();
    cur ^= 1;
  }
#undef STAGE

  ushort_t* op = z ? o1p : o0p;
#pragma unroll
  for (int qg = 0; qg < 2; qg++) {
    if (c == 0) {
#pragma unroll
      for (int r = 0; r < 4; r++)
        lpart[((size_t)z * 24 + bh) * SDIM + q0 + qg * 16 + 4 * g + r] =
            accL[qg][r];
    }
#pragma unroll
    for (int dt = 0; dt < 4; dt++)
#pragma unroll
      for (int r = 0; r < 4; r++) {
        int s = q0 + qg * 16 + 4 * g + r;
        op[((size_t)(bb * SDIM + s)) * EDIM + h * 64 + dt * 16 + c] =
            f2bf(accO[qg][dt][r]);
      }
  }
}

// ---------- combine split-KV partials: vals = (O0+O1)/(l0+l1) ----------
__global__ __launch_bounds__(256) void k_comb(const ushort_t* __restrict__ o0p,
                                              const ushort_t* __restrict__ o1p,
                                              const float* __restrict__ lpart,
                                              ushort_t* __restrict__ vals) {
  const int gid = blockIdx.x * 256 + threadIdx.x; // < 4096*96
  const int tok = gid / 96, ch = gid - tok * 96;
  const int h = ch >> 3;
  const int bb = tok >> 11, s = tok & 2047;
  const size_t lrow = (size_t)(bb * 12 + h) * SDIM + s;
  const float inv = 1.f / (lpart[lrow] + lpart[(size_t)24 * SDIM + lrow]);
  short8 a = *(const short8*)(o0p + (size_t)gid * 8);
  short8 b = *(const short8*)(o1p + (size_t)gid * 8);
  short8 o;
#pragma unroll
  for (int j = 0; j < 8; j++)
    o[j] = (short)f2bf((bf2f((ushort_t)a[j]) + bf2f((ushort_t)b[j])) * inv);
  *(short8*)(vals + (size_t)gid * 8) = o;
}

// ---------- final: out = x2(bf16) + b2 + p0 + p1 (MLP2 split-K combine) ------
__global__ __launch_bounds__(256) void k_fin(const ushort_t* __restrict__ x2b,
                                             const float* __restrict__ b2,
                                             const ushort_t* __restrict__ p,
                                             float* __restrict__ out) {
  const int i = blockIdx.x * 256 + threadIdx.x; // < 786432 (f32x4 groups)
  s16x4 rx = ((const s16x4*)x2b)[i];
  f32x4 b = ((const f32x4*)b2)[i % 192];
  s16x4 a0 = ((const s16x4*)p)[i];
  s16x4 a1 = ((const s16x4*)(p + (size_t)NTOK * 768))[i];
  f32x4 o;
#pragma unroll
  for (int j = 0; j < 4; j++)
    o[j] = bf2f((ushort_t)rx[j]) + b[j] + bf2f((ushort_t)a0[j]) +
           bf2f((ushort_t)a1[j]);
  ((f32x4*)out)[i] = o;
}

extern "C" void kernel_launch(void* const* d_in, const int* in_sizes, int n_in,
                              void* d_out, int out_size, void* d_ws, size_t ws_size,
                              hipStream_t stream) {
  const float* x = (const float*)d_in[0];
  const float* ln1g = (const float*)d_in[1];
  const float* ln1b = (const float*)d_in[2];
  const float* wq = (const float*)d_in[3];
  const float* bq = (const float*)d_in[4];
  const float* wk = (const float*)d_in[5];
  const float* bk = (const float*)d_in[6];
  const float* wv = (const float*)d_in[7];
  const float* bv = (const float*)d_in[8];
  const float* wo = (const float*)d_in[9];
  const float* bo = (const float*)d_in[10];
  const float* ln2g = (const float*)d_in[11];
  const float* ln2b = (const float*)d_in[12];
  const float* w1 = (const float*)d_in[13];
  const float* b1 = (const float*)d_in[14];
  const float* wvqc = (const float*)d_in[15];
  const float* bvqc = (const float*)d_in[16];
  const float* w2 = (const float*)d_in[17];
  const float* b2 = (const float*)d_in[18];
  float* out = (float*)d_out;

  char* w = (char*)d_ws;
  ushort_t* xn = (ushort_t*)(w + 0);           // 6291456 (dead after QKV gemm)
  ushort_t* xn2 = (ushort_t*)(w + 6291456);    // 6291456; Opart1 before LN2
  ushort_t* opart1 = (ushort_t*)(w + 6291456);
  ushort_t* x2b = (ushort_t*)(w + 12582912);   // bf16 residual, 6291456
  ushort_t* qb = (ushort_t*)(w + 25165824);    // 6291456
  ushort_t* kb = (ushort_t*)(w + 31457280);    // 6291456
  ushort_t* vb = (ushort_t*)(w + 37748736);    // 6291456 (V^T psi layout)
  ushort_t* vals = (ushort_t*)(w + 44040192);  // 6291456; Opart0 (in-place comb)
  ushort_t* G = (ushort_t*)(w + 25165824);     // overlays q..vals
  ushort_t* wqkvT = (ushort_t*)(w + 50528256); // 3538944
  ushort_t* woT = (ushort_t*)(w + 54067200);   // 1179648
  ushort_t* wvqcT = (ushort_t*)(w + 55246848); // 1179648
  ushort_t* w1s = (ushort_t*)(w + 56426496);   // 4718592; lpart after W1eff gemm
  float* lpart = (float*)(w + 56426496);       // 393216 (dead w1s)
  ushort_t* W1eT = (ushort_t*)(w + 61145088);  // 4718592
  float* b1e = (float*)(w + 65863680);         // 12288
  ushort_t* w2T = (ushort_t*)(w + 65875968);   // 4718592 -> end 70594560
  ushort_t* mp = (ushort_t*)(w + 0); // MLP2 partials [2][4096*768] bf16

  dim3 tb(32, 8);
  // merged preprocessing: weight transposes + w1 shifts + LayerNorm1
  k_pre<<<dim3(24, 321), tb, 0, stream>>>(wq, wk, wv, wo, wvqc, w2, w1, x, ln1g,
                                          ln1b, wqkvT, woT, wvqcT, w2T, w1s, xn);
  // W1effT[j*4+i][e] = sum_m wvqcT[j][m] * w1s[i][e][m]
  k_gemm<3, 64, 64, 64><<<dim3(12, 12, 4), 256, 0, stream>>>(
      wvqcT, w1s, 768, 768, 768, nullptr, nullptr, nullptr, nullptr, nullptr,
      W1eT, nullptr, nullptr, 768);
  // QKV: V written directly as V^T psi-permuted (k_vT fused away)
  k_gemm<0, 128, 64, 64><<<dim3(32, 36), 256, 0, stream>>>(
      xn, wqkvT, 768, 768, 768, bq, bk, bv, nullptr, nullptr, qb, kb, vb, 0);
  // xn dead from here. w1s dead; lpart overlays it.
  k_attn<<<dim3(16, 24, 2), 256, 0, stream>>>(qb, kb, vb, vals, opart1, lpart);
  k_comb<<<1536, 256, 0, stream>>>(vals, opart1, lpart, vals);
  // x2b = bf16(x + vals @ woT + bo)  (MODE 6)
  k_gemm<6, 64, 64, 64><<<dim3(64, 12), 256, 0, stream>>>(
      vals, woT, 768, 768, 768, bo, nullptr, nullptr, nullptr, x, x2b, nullptr,
      nullptr, 768);
  // LN2 (+fused b1eff reduction in extra blocks)
  k_lnb<<<7168, 256, 0, stream>>>(x2b, ln2g, ln2b, xn2, b1, wvqcT, bvqc, b1e);
  k_gemm<2, 128, 64, 64><<<dim3(32, 48), 256, 0, stream>>>(
      xn2, W1eT, 768, 768, 768, b1e, nullptr, nullptr, nullptr, nullptr, G,
      nullptr, nullptr, 3072);
  // MLP2 split-K=2: bf16 partials (direct store) then combine with resid+bias
  k_gemm<5, 64, 64, 64><<<dim3(64, 12, 2), 256, 0, stream>>>(
      G, w2T, 3072, 3072, 1536, nullptr, nullptr, nullptr, nullptr, nullptr, mp,
      nullptr, nullptr, 768);
  k_fin<<<3072, 256, 0, stream>>>(x2b, b2, mp, out);
}

// Round 27
// 186.361 us; speedup vs baseline: 1.0375x; 1.0023x over previous
//
#include <hip/hip_runtime.h>
#include <hip/hip_bf16.h>
#include <math.h>

typedef unsigned short ushort_t; // bf16 bits
typedef __attribute__((ext_vector_type(4))) short s16x4;
typedef __attribute__((ext_vector_type(8))) short short8;
typedef __attribute__((ext_vector_type(8))) __bf16 bf16x8;
typedef __attribute__((ext_vector_type(4))) float f32x4;
typedef __attribute__((ext_vector_type(4))) unsigned u32x4;

#define SDIM 2048
#define EDIM 768
#define NTOK 4096

static __device__ __forceinline__ ushort_t f2bf(float f) {
  unsigned u = __builtin_bit_cast(unsigned, f);
  u += 0x7fff + ((u >> 16) & 1);
  return (ushort_t)(u >> 16);
}
static __device__ __forceinline__ float bf2f(ushort_t h) {
  return __builtin_bit_cast(float, (unsigned)h << 16);
}
static __device__ __forceinline__ f32x4 mfma16(short8 a, short8 b, f32x4 c) {
  return __builtin_amdgcn_mfma_f32_16x16x32_bf16(
      __builtin_bit_cast(bf16x8, a), __builtin_bit_cast(bf16x8, b), c, 0, 0, 0);
}
static __device__ __forceinline__ void gload_lds16(const void* g, void* l) {
  __builtin_amdgcn_global_load_lds(
      (const __attribute__((address_space(1))) void*)g,
      (__attribute__((address_space(3))) void*)l, 16, 0, 0);
}
static __device__ __forceinline__ unsigned cvtpk(float lo, float hi) {
  unsigned r;
  asm("v_cvt_pk_bf16_f32 %0, %1, %2" : "=v"(r) : "v"(lo), "v"(hi));
  return r;
}
static __device__ __forceinline__ float exp2fast(float x) {
  float r;
  asm("v_exp_f32 %0, %1" : "=v"(r) : "v"(x));
  return r;
}

// ---------- merged preprocessing ----------
// grid (24, 321), block (32,8):
//   y in [0,30): five 768x768 transposes, 128x32 strips (y/6 selects weight)
//   y in [30,54): w2 [3072][768] -> w2T, 128x32 strips
//   y in [54,150): w1 shifted copies w1s[i][e][m] = w1[e][i+m]
//   y in [150,321): LayerNorm1 rows (row = (y-150)*24 + blockIdx.x)
__global__ void k_pre(const float* __restrict__ wq, const float* __restrict__ wk,
                      const float* __restrict__ wv, const float* __restrict__ wo,
                      const float* __restrict__ wvqc, const float* __restrict__ w2,
                      const float* __restrict__ w1, const float* __restrict__ x,
                      const float* __restrict__ ln1g, const float* __restrict__ ln1b,
                      ushort_t* __restrict__ oqkv, ushort_t* __restrict__ owo,
                      ushort_t* __restrict__ ovqc, ushort_t* __restrict__ w2T,
                      ushort_t* __restrict__ w1s, ushort_t* __restrict__ xn) {
  const int y = blockIdx.y;
  const int tx = threadIdx.x, ty = threadIdx.y;
  __shared__ float tile[128][33];
  __shared__ float red[8];
  if (y < 54) {
    const float* in;
    ushort_t* out;
    int R, r0;
    const int c0 = blockIdx.x * 32;
    if (y < 30) {
      const int z = y / 6, ry = y - z * 6;
      in = z == 0 ? wq : z == 1 ? wk : z == 2 ? wv : z == 3 ? wo : wvqc;
      out = z < 3 ? oqkv + (size_t)z * 768 * 768 : (z == 3 ? owo : ovqc);
      R = 768;
      r0 = ry * 128;
    } else {
      in = w2;
      out = w2T;
      R = 3072;
      r0 = (y - 30) * 128;
    }
#pragma unroll
    for (int i = 0; i < 128; i += 8)
      tile[i + ty][tx] = in[(size_t)(r0 + i + ty) * 768 + c0 + tx];
    __syncthreads();
#pragma unroll
    for (int i = 0; i < 32; i += 8) {
      s16x4 v;
#pragma unroll
      for (int j = 0; j < 4; j++) v[j] = (short)f2bf(tile[tx * 4 + j][i + ty]);
      *(s16x4*)(out + (size_t)(c0 + i + ty) * R + r0 + tx * 4) = v;
    }
  } else if (y < 150) {
    const int idx = ((y - 54) * 24 + blockIdx.x) * 256 + ty * 32 + tx;
    const int e = idx / 768, m = idx - (idx / 768) * 768;
#pragma unroll
    for (int i = 0; i < 4; i++)
      w1s[((size_t)i * 768 + e) * 768 + m] = f2bf(w1[(size_t)e * 3072 + i + m]);
  } else {
    const int row = (y - 150) * 24 + blockIdx.x;
    if (row >= NTOK) return;
    const int t = ty * 32 + tx;
    const float* xr = x + (size_t)row * EDIM;
    float v0 = xr[t], v1 = xr[t + 256], v2 = xr[t + 512];
    float s = v0 + v1 + v2;
    float s2 = v0 * v0 + v1 * v1 + v2 * v2;
#pragma unroll
    for (int m = 32; m; m >>= 1) {
      s += __shfl_xor(s, m);
      s2 += __shfl_xor(s2, m);
    }
    const int wid = t >> 6, lane = t & 63;
    if (lane == 0) { red[wid] = s; red[4 + wid] = s2; }
    __syncthreads();
    s = red[0] + red[1] + red[2] + red[3];
    s2 = red[4] + red[5] + red[6] + red[7];
    float mean = s * (1.f / EDIM);
    float var = s2 * (1.f / EDIM) - mean * mean;
    float rstd = rsqrtf(var + 1e-5f);
    ushort_t* orow = xn + (size_t)row * EDIM;
    orow[t] = f2bf((v0 - mean) * rstd * ln1g[t] + ln1b[t]);
    orow[t + 256] = f2bf((v1 - mean) * rstd * ln1g[t + 256] + ln1b[t + 256]);
    orow[t + 512] = f2bf((v2 - mean) * rstd * ln1g[t + 512] + ln1b[t + 512]);
  }
}

// ---------- LayerNorm2 (bf16 in/out) + fused b1eff reduction ----------
// grid 7168: blocks [0,4096) do LN rows; blocks [4096,7168) compute
// b1eff[n] = sum_m b1[i+m]*wvqcT[j][m] + bvqc[j]  (n = blockIdx.x-4096)
__global__ __launch_bounds__(256) void k_lnb(const ushort_t* __restrict__ x,
                                             const float* __restrict__ gam,
                                             const float* __restrict__ bet,
                                             ushort_t* __restrict__ out,
                                             const float* __restrict__ b1,
                                             const ushort_t* __restrict__ wvqcT,
                                             const float* __restrict__ bvqc,
                                             float* __restrict__ b1e) {
  const int t = threadIdx.x;
  __shared__ float red[8];
  if (blockIdx.x < NTOK) {
    const int row = blockIdx.x;
    const ushort_t* xr = x + (size_t)row * EDIM;
    float v0 = bf2f(xr[t]), v1 = bf2f(xr[t + 256]), v2 = bf2f(xr[t + 512]);
    float s = v0 + v1 + v2;
    float s2 = v0 * v0 + v1 * v1 + v2 * v2;
#pragma unroll
    for (int m = 32; m; m >>= 1) {
      s += __shfl_xor(s, m);
      s2 += __shfl_xor(s2, m);
    }
    const int wid = t >> 6, lane = t & 63;
    if (lane == 0) { red[wid] = s; red[4 + wid] = s2; }
    __syncthreads();
    s = red[0] + red[1] + red[2] + red[3];
    s2 = red[4] + red[5] + red[6] + red[7];
    float mean = s * (1.f / EDIM);
    float var = s2 * (1.f / EDIM) - mean * mean;
    float rstd = rsqrtf(var + 1e-5f);
    ushort_t* orow = out + (size_t)row * EDIM;
    orow[t] = f2bf((v0 - mean) * rstd * gam[t] + bet[t]);
    orow[t + 256] = f2bf((v1 - mean) * rstd * gam[t + 256] + bet[t + 256]);
    orow[t + 512] = f2bf((v2 - mean) * rstd * gam[t + 512] + bet[t + 512]);
  } else {
    const int n = blockIdx.x - NTOK; // < 3072
    const int i = n & 3, j = n >> 2;
    float s = 0.f;
    for (int m = t; m < 768; m += 256)
      s += b1[i + m] * bf2f(wvqcT[(size_t)j * 768 + m]);
#pragma unroll
    for (int mm = 32; mm; mm >>= 1) s += __shfl_xor(s, mm);
    const int wid = t >> 6, lane = t & 63;
    if (lane == 0) red[wid] = s;
    __syncthreads();
    if (t == 0) b1e[n] = red[0] + red[1] + red[2] + red[3] + bvqc[j];
  }
}

// ---------- GEMM, templated BK, T2 swizzled LDS, 32KB double-buffer ----------
// 0: QKV scatter (+bias; V written transposed+psi-permuted as [bh][d][psi(t)])
// 1: f32 out = resid + acc + bias     2: gelu(acc+bias) -> bf16
// 3: W1effT store row*4+z             5: split-K partial -> bf16 buffer z
// 6: bf16 out = resid(f32) + acc + bias
template <int MODE, int BM, int BN, int BK>
__global__ __launch_bounds__(256) void k_gemm(
    const ushort_t* __restrict__ A, const ushort_t* __restrict__ Bt, int lda,
    int ldb, int kc, const float* __restrict__ b0, const float* __restrict__ b1p,
    const float* __restrict__ b2p, float* __restrict__ outF,
    const float* __restrict__ resid, ushort_t* __restrict__ o0,
    ushort_t* __restrict__ o1, ushort_t* __restrict__ o2, int ldc) {
  constexpr int MT = BM / 32, NT = BN / 32; // frags per wave (2x2 wave grid)
  constexpr int KCH = BK / 8;               // 16B chunks per row
  constexpr int NPA = BM * BK / 2048;       // staging passes (4KB each)
  constexpr int NPB = BN * BK / 2048;
  constexpr int ROWSP = 2048 / BK;          // rows per staging pass
  constexpr int KK = BK / 32;
  __shared__ ushort_t As[2][BM * BK];
  __shared__ ushort_t Bs[2][BN * BK];
  const int t = threadIdx.x;
  const int m0 = blockIdx.x * BM, n0 = blockIdx.y * BN;
  if (MODE == 3) Bt += (size_t)blockIdx.z * 768 * 768;
  const int koff = (MODE == 5) ? blockIdx.z * kc : 0;
  const int srow = t / KCH, sch = t % KCH;
  const int xs = (BK == 64) ? (srow & 7) : ((srow >> 1) & 3);
  const int gseg = (sch ^ xs) * 8; // inverse-swizzled global chunk
  const ushort_t* ga = A + (size_t)(m0 + srow) * lda + koff + gseg;
  const ushort_t* gb = Bt + (size_t)(n0 + srow) * ldb + koff + gseg;
  const int ldst = t * 8;
  const int lane = t & 63, wid = t >> 6;
  const int g = lane >> 4, c = lane & 15;
  const int wm = (wid >> 1) * (BM / 2), wn = (wid & 1) * (BN / 2);
  const int xc = (BK == 64) ? (c & 7) : ((c >> 1) & 3);
  f32x4 acc[MT][NT] = {};

#define STAGE(BUF, K0)                                                           \
  {                                                                              \
    _Pragma("unroll") for (int p = 0; p < NPA; p++)                              \
        gload_lds16(ga + (K0) + (size_t)(p * ROWSP) * lda,                       \
                    As[BUF] + p * 2048 + ldst);                                  \
    _Pragma("unroll") for (int p = 0; p < NPB; p++)                              \
        gload_lds16(gb + (K0) + (size_t)(p * ROWSP) * ldb,                       \
                    Bs[BUF] + p * 2048 + ldst);                                  \
  }

  STAGE(0, 0);
  __syncthreads();
  int cur = 0;
  for (int k0 = 0; k0 < kc; k0 += BK) {
    if (k0 + BK < kc) STAGE(cur ^ 1, k0 + BK);
    short8 af[KK][MT], bfr[KK][NT];
#pragma unroll
    for (int kk = 0; kk < KK; kk++) {
#pragma unroll
      for (int mt = 0; mt < MT; mt++)
        af[kk][mt] = *(const short8*)(As[cur] + (wm + mt * 16 + c) * BK +
                                      (((g + kk * 4) ^ xc) * 8));
#pragma unroll
      for (int nt = 0; nt < NT; nt++)
        bfr[kk][nt] = *(const short8*)(Bs[cur] + (wn + nt * 16 + c) * BK +
                                       (((g + kk * 4) ^ xc) * 8));
    }
    __builtin_amdgcn_s_setprio(1);
#pragma unroll
    for (int kk = 0; kk < KK; kk++)
#pragma unroll
      for (int mt = 0; mt < MT; mt++)
#pragma unroll
        for (int nt = 0; nt < NT; nt++)
          acc[mt][nt] = mfma16(af[kk][mt], bfr[kk][nt], acc[mt][nt]);
    __builtin_amdgcn_s_setprio(0);
    __syncthreads();
    cur ^= 1;
  }
#undef STAGE

  if constexpr (MODE == 0) {
#pragma unroll
    for (int mt = 0; mt < MT; mt++) {
#pragma unroll
      for (int nt = 0; nt < NT; nt++) {
        const int row0 = m0 + wm + mt * 16 + g * 4;
        const int col = n0 + wn + nt * 16 + c;
        const int which = col / 768; // block-uniform (BN=64 | 768)
        const int nn = col - which * 768;
        const int h = nn >> 6, d = nn & 63;
        const int bb = row0 >> 11, s0 = row0 & 2047;
        if (which == 2) {
          // V: transposed + psi-permuted store, 4 consecutive tokens -> 8B
          const int tl = s0 & 63;
          const int tp = (s0 & ~63) + 32 * (tl >> 5) + 8 * ((tl >> 2) & 3) +
                         4 * ((tl >> 4) & 1);
          s16x4 pv;
#pragma unroll
          for (int r = 0; r < 4; r++)
            pv[r] = (short)f2bf(acc[mt][nt][r] + b2p[nn]);
          *(s16x4*)(o2 + ((size_t)(bb * 12 + h) * 64 + d) * SDIM + tp) = pv;
        } else {
          const float* bp = which == 0 ? b0 : b1p;
          ushort_t* dp = which == 0 ? o0 : o1;
#pragma unroll
          for (int r = 0; r < 4; r++)
            dp[((size_t)(bb * 12 + h) * SDIM + s0 + r) * 64 + d] =
                f2bf(acc[mt][nt][r] + bp[nn]);
        }
      }
    }
    return;
  }

#pragma unroll
  for (int mt = 0; mt < MT; mt++) {
#pragma unroll
    for (int nt = 0; nt < NT; nt++) {
#pragma unroll
      for (int r = 0; r < 4; r++) {
        int row = m0 + wm + mt * 16 + g * 4 + r;
        int col = n0 + wn + nt * 16 + c;
        float val = acc[mt][nt][r];
        if constexpr (MODE == 1) {
          size_t o = (size_t)row * ldc + col;
          outF[o] = resid[o] + val + b0[col];
        } else if constexpr (MODE == 2) {
          float xg = val + b0[col];
          float z2 = xg * (1.5957691216f + 0.0713548162f * xg * xg);
          float ge = xg / (1.f + __expf(-z2));
          o0[(size_t)row * ldc + col] = f2bf(ge);
        } else if constexpr (MODE == 5) {
          o0[(size_t)blockIdx.z * (NTOK * 768) + (size_t)row * ldc + col] =
              f2bf(val);
        } else if constexpr (MODE == 6) {
          size_t o = (size_t)row * ldc + col;
          o0[o] = f2bf(resid[o] + val + b0[col]);
        } else {
          o0[((size_t)row * 4 + blockIdx.z) * ldc + col] = f2bf(val);
        }
      }
    }
  }
}

// ---------- flash attention v9: 32 q-rows/wave, split-KV x2, inline q-norm ----
__global__ __launch_bounds__(256) void k_attn(
    const ushort_t* __restrict__ q, const ushort_t* __restrict__ k,
    const ushort_t* __restrict__ vt, ushort_t* __restrict__ o0p,
    ushort_t* __restrict__ o1p, float* __restrict__ lpart) {
  const int tid = threadIdx.x;
  const int wid = tid >> 6, lane = tid & 63;
  const int g = lane >> 4, c = lane & 15;
  const int bh = blockIdx.y;
  const int z = blockIdx.z;
  const int tbase = z * (SDIM / 2);
  const int q0 = blockIdx.x * 128 + wid * 32;
  const int bb = bh / 12, h = bh - bb * 12;
  const ushort_t* qb = q + (size_t)bh * SDIM * 64;
  const ushort_t* kb = k + (size_t)bh * SDIM * 64;
  const ushort_t* vb = vt + (size_t)bh * 64 * SDIM;

  __shared__ ushort_t Ks[2][64 * 64]; // linear, swizzled content
  __shared__ ushort_t Vs[2][64 * 64];

  short8 bq[2][2];
#pragma unroll
  for (int qg = 0; qg < 2; qg++) {
    short8 a0 = *(const short8*)(qb + (size_t)(q0 + qg * 16 + c) * 64 + g * 8);
    short8 a1 =
        *(const short8*)(qb + (size_t)(q0 + qg * 16 + c) * 64 + 32 + g * 8);
    float s = 0.f;
#pragma unroll
    for (int j = 0; j < 8; j++) {
      float f0 = bf2f((ushort_t)a0[j]), f1 = bf2f((ushort_t)a1[j]);
      s += f0 * f0 + f1 * f1;
    }
    s += __shfl_xor(s, 16);
    s += __shfl_xor(s, 32);
    const float scq = rsqrtf(64.f * fmaxf(s, 1e-5f)) * 1.44269504089f;
#pragma unroll
    for (int j = 0; j < 8; j++) {
      bq[qg][0][j] = (short)f2bf(bf2f((ushort_t)a0[j]) * scq);
      bq[qg][1][j] = (short)f2bf(bf2f((ushort_t)a1[j]) * scq);
    }
  }
  const short8 ones = {0x3F80, 0x3F80, 0x3F80, 0x3F80,
                       0x3F80, 0x3F80, 0x3F80, 0x3F80}; // bf16 1.0 x8

  const int srow = tid >> 3, sj = tid & 7;

#define STAGE(BUF, T0)                                                          \
  {                                                                             \
    _Pragma("unroll") for (int n = 0; n < 2; n++) {                             \
      const int row = n * 32 + srow;                                            \
      const int scol = (sj ^ (row & 7)) * 8;                                    \
      gload_lds16(kb + (size_t)((T0) + row) * 64 + scol,                        \
                  Ks[BUF] + n * 2048 + tid * 8);                                \
      gload_lds16(vb + (size_t)row * SDIM + (T0) + scol,                        \
                  Vs[BUF] + n * 2048 + tid * 8);                                \
    }                                                                           \
  }

  f32x4 accO[2][4] = {};
  f32x4 accL[2] = {};
  const int sw = (c & 7) << 4;

  STAGE(0, tbase);
  __syncthreads();
  int cur = 0;
  for (int tt = 0; tt < SDIM / 128; tt++) {
    const int t0 = tbase + tt * 64;
    if (tt + 1 < SDIM / 128) STAGE(cur ^ 1, t0 + 64);
    const char* Kc = (const char*)Ks[cur];
    const char* Vc = (const char*)Vs[cur];
    f32x4 s0[4] = {}, s1[4] = {};
    __builtin_amdgcn_s_setprio(1);
#pragma unroll
    for (int i = 0; i < 4; i++) {
      const int rb = (i * 16 + c) * 128;
      short8 ka0 = *(const short8*)(Kc + rb + ((g * 16) ^ sw));
      short8 ka1 = *(const short8*)(Kc + rb + ((64 + g * 16) ^ sw));
      s0[i] = mfma16(ka0, bq[0][0], s0[i]);
      s1[i] = mfma16(ka0, bq[1][0], s1[i]);
      s0[i] = mfma16(ka1, bq[0][1], s0[i]);
      s1[i] = mfma16(ka1, bq[1][1], s1[i]);
    }
    __builtin_amdgcn_s_setprio(0);
    u32x4 w00 = {cvtpk(exp2fast(s0[0][0]), exp2fast(s0[0][1])),
                 cvtpk(exp2fast(s0[0][2]), exp2fast(s0[0][3])),
                 cvtpk(exp2fast(s0[1][0]), exp2fast(s0[1][1])),
                 cvtpk(exp2fast(s0[1][2]), exp2fast(s0[1][3]))};
    u32x4 w10 = {cvtpk(exp2fast(s1[0][0]), exp2fast(s1[0][1])),
                 cvtpk(exp2fast(s1[0][2]), exp2fast(s1[0][3])),
                 cvtpk(exp2fast(s1[1][0]), exp2fast(s1[1][1])),
                 cvtpk(exp2fast(s1[1][2]), exp2fast(s1[1][3]))};
    u32x4 w01 = {cvtpk(exp2fast(s0[2][0]), exp2fast(s0[2][1])),
                 cvtpk(exp2fast(s0[2][2]), exp2fast(s0[2][3])),
                 cvtpk(exp2fast(s0[3][0]), exp2fast(s0[3][1])),
                 cvtpk(exp2fast(s0[3][2]), exp2fast(s0[3][3]))};
    u32x4 w11 = {cvtpk(exp2fast(s1[2][0]), exp2fast(s1[2][1])),
                 cvtpk(exp2fast(s1[2][2]), exp2fast(s1[2][3])),
                 cvtpk(exp2fast(s1[3][0]), exp2fast(s1[3][1])),
                 cvtpk(exp2fast(s1[3][2]), exp2fast(s1[3][3]))};
    short8 pa00 = __builtin_bit_cast(short8, w00);
    short8 pa01 = __builtin_bit_cast(short8, w01);
    short8 pa10 = __builtin_bit_cast(short8, w10);
    short8 pa11 = __builtin_bit_cast(short8, w11);
    __builtin_amdgcn_s_setprio(1);
    accL[0] = mfma16(pa00, ones, accL[0]);
    accL[1] = mfma16(pa10, ones, accL[1]);
    accL[0] = mfma16(pa01, ones, accL[0]);
    accL[1] = mfma16(pa11, ones, accL[1]);
#pragma unroll
    for (int dt = 0; dt < 4; dt++) {
      const int vbse = (dt * 16 + c) * 128;
      short8 v0 = *(const short8*)(Vc + vbse + ((g * 16) ^ sw));
      short8 v1 = *(const short8*)(Vc + vbse + ((64 + g * 16) ^ sw));
      accO[0][dt] = mfma16(pa00, v0, accO[0][dt]);
      accO[1][dt] = mfma16(pa10, v0, accO[1][dt]);
      accO[0][dt] = mfma16(pa01, v1, accO[0][dt]);
      accO[1][dt] = mfma16(pa11, v1, accO[1][dt]);
    }
    __builtin_amdgcn_s_setprio(0);
    __syncthreads();
    cur ^= 1;
  }
#undef STAGE

  ushort_t* op = z ? o1p : o0p;
#pragma unroll
  for (int qg = 0; qg < 2; qg++) {
    if (c == 0) {
#pragma unroll
      for (int r = 0; r < 4; r++)
        lpart[((size_t)z * 24 + bh) * SDIM + q0 + qg * 16 + 4 * g + r] =
            accL[qg][r];
    }
#pragma unroll
    for (int dt = 0; dt < 4; dt++)
#pragma unroll
      for (int r = 0; r < 4; r++) {
        int s = q0 + qg * 16 + 4 * g + r;
        op[((size_t)(bb * SDIM + s)) * EDIM + h * 64 + dt * 16 + c] =
            f2bf(accO[qg][dt][r]);
      }
  }
}

// ---------- combine split-KV partials: vals = (O0+O1)/(l0+l1) ----------
__global__ __launch_bounds__(256) void k_comb(const ushort_t* __restrict__ o0p,
                                              const ushort_t* __restrict__ o1p,
                                              const float* __restrict__ lpart,
                                              ushort_t* __restrict__ vals) {
  const int gid = blockIdx.x * 256 + threadIdx.x; // < 4096*96
  const int tok = gid / 96, ch = gid - tok * 96;
  const int h = ch >> 3;
  const int bb = tok >> 11, s = tok & 2047;
  const size_t lrow = (size_t)(bb * 12 + h) * SDIM + s;
  const float inv = 1.f / (lpart[lrow] + lpart[(size_t)24 * SDIM + lrow]);
  short8 a = *(const short8*)(o0p + (size_t)gid * 8);
  short8 b = *(const short8*)(o1p + (size_t)gid * 8);
  short8 o;
#pragma unroll
  for (int j = 0; j < 8; j++)
    o[j] = (short)f2bf((bf2f((ushort_t)a[j]) + bf2f((ushort_t)b[j])) * inv);
  *(short8*)(vals + (size_t)gid * 8) = o;
}

// ---------- final: out = x2(bf16) + b2 + p0 + p1 (MLP2 split-K combine) ------
__global__ __launch_bounds__(256) void k_fin(const ushort_t* __restrict__ x2b,
                                             const float* __restrict__ b2,
                                             const ushort_t* __restrict__ p,
                                             float* __restrict__ out) {
  const int i = blockIdx.x * 256 + threadIdx.x; // < 786432 (f32x4 groups)
  s16x4 rx = ((const s16x4*)x2b)[i];
  f32x4 b = ((const f32x4*)b2)[i % 192];
  s16x4 a0 = ((const s16x4*)p)[i];
  s16x4 a1 = ((const s16x4*)(p + (size_t)NTOK * 768))[i];
  f32x4 o;
#pragma unroll
  for (int j = 0; j < 4; j++)
    o[j] = bf2f((ushort_t)rx[j]) + b[j] + bf2f((ushort_t)a0[j]) +
           bf2f((ushort_t)a1[j]);
  ((f32x4*)out)[i] = o;
}

extern "C" void kernel_launch(void* const* d_in, const int* in_sizes, int n_in,
                              void* d_out, int out_size, void* d_ws, size_t ws_size,
                              hipStream_t stream) {
  const float* x = (const float*)d_in[0];
  const float* ln1g = (const float*)d_in[1];
  const float* ln1b = (const float*)d_in[2];
  const float* wq = (const float*)d_in[3];
  const float* bq = (const float*)d_in[4];
  const float* wk = (const float*)d_in[5];
  const float* bk = (const float*)d_in[6];
  const float* wv = (const float*)d_in[7];
  const float* bv = (const float*)d_in[8];
  const float* wo = (const float*)d_in[9];
  const float* bo = (const float*)d_in[10];
  const float* ln2g = (const float*)d_in[11];
  const float* ln2b = (const float*)d_in[12];
  const float* w1 = (const float*)d_in[13];
  const float* b1 = (const float*)d_in[14];
  const float* wvqc = (const float*)d_in[15];
  const float* bvqc = (const float*)d_in[16];
  const float* w2 = (const float*)d_in[17];
  const float* b2 = (const float*)d_in[18];
  float* out = (float*)d_out;

  char* w = (char*)d_ws;
  ushort_t* xn = (ushort_t*)(w + 0);           // 6291456 (dead after QKV gemm)
  ushort_t* xn2 = (ushort_t*)(w + 6291456);    // 6291456; Opart1 before LN2
  ushort_t* opart1 = (ushort_t*)(w + 6291456);
  ushort_t* x2b = (ushort_t*)(w + 12582912);   // bf16 residual, 6291456
  ushort_t* qb = (ushort_t*)(w + 25165824);    // 6291456
  ushort_t* kb = (ushort_t*)(w + 31457280);    // 6291456
  ushort_t* vb = (ushort_t*)(w + 37748736);    // 6291456 (V^T psi layout)
  ushort_t* vals = (ushort_t*)(w + 44040192);  // 6291456; Opart0 (in-place comb)
  ushort_t* G = (ushort_t*)(w + 25165824);     // overlays q..vals
  ushort_t* wqkvT = (ushort_t*)(w + 50528256); // 3538944
  ushort_t* woT = (ushort_t*)(w + 54067200);   // 1179648
  ushort_t* wvqcT = (ushort_t*)(w + 55246848); // 1179648
  ushort_t* w1s = (ushort_t*)(w + 56426496);   // 4718592; lpart after W1eff gemm
  float* lpart = (float*)(w + 56426496);       // 393216 (dead w1s)
  ushort_t* W1eT = (ushort_t*)(w + 61145088);  // 4718592
  float* b1e = (float*)(w + 65863680);         // 12288
  ushort_t* w2T = (ushort_t*)(w + 65875968);   // 4718592 -> end 70594560
  ushort_t* mp = (ushort_t*)(w + 0); // MLP2 partials [2][4096*768] bf16

  dim3 tb(32, 8);
  // merged preprocessing: weight transposes + w1 shifts + LayerNorm1
  k_pre<<<dim3(24, 321), tb, 0, stream>>>(wq, wk, wv, wo, wvqc, w2, w1, x, ln1g,
                                          ln1b, wqkvT, woT, wvqcT, w2T, w1s, xn);
  // W1effT[j*4+i][e] = sum_m wvqcT[j][m] * w1s[i][e][m]
  k_gemm<3, 64, 64, 64><<<dim3(12, 12, 4), 256, 0, stream>>>(
      wvqcT, w1s, 768, 768, 768, nullptr, nullptr, nullptr, nullptr, nullptr,
      W1eT, nullptr, nullptr, 768);
  // QKV: V written directly as V^T psi-permuted (k_vT fused away)
  k_gemm<0, 128, 64, 64><<<dim3(32, 36), 256, 0, stream>>>(
      xn, wqkvT, 768, 768, 768, bq, bk, bv, nullptr, nullptr, qb, kb, vb, 0);
  // xn dead from here. w1s dead; lpart overlays it.
  k_attn<<<dim3(16, 24, 2), 256, 0, stream>>>(qb, kb, vb, vals, opart1, lpart);
  k_comb<<<1536, 256, 0, stream>>>(vals, opart1, lpart, vals);
  // x2b = bf16(x + vals @ woT + bo)  (MODE 6)
  k_gemm<6, 64, 64, 64><<<dim3(64, 12), 256, 0, stream>>>(
      vals, woT, 768, 768, 768, bo, nullptr, nullptr, nullptr, x, x2b, nullptr,
      nullptr, 768);
  // LN2 (+fused b1eff reduction in extra blocks)
  k_lnb<<<7168, 256, 0, stream>>>(x2b, ln2g, ln2b, xn2, b1, wvqcT, bvqc, b1e);
  k_gemm<2, 128, 64, 64><<<dim3(32, 48), 256, 0, stream>>>(
      xn2, W1eT, 768, 768, 768, b1e, nullptr, nullptr, nullptr, nullptr, G,
      nullptr, nullptr, 3072);
  // MLP2 split-K=2: bf16 partials (direct store) then combine with resid+bias
  k_gemm<5, 64, 64, 64><<<dim3(64, 12, 2), 256, 0, stream>>>(
      G, w2T, 3072, 3072, 1536, nullptr, nullptr, nullptr, nullptr, nullptr, mp,
      nullptr, nullptr, 768);
  k_fin<<<3072, 256, 0, stream>>>(x2b, b2, mp, out);
}